// Round 2
// baseline (304.850 us; speedup 1.0000x reference)
//
#include <hip/hip_runtime.h>

// ---------------------------------------------------------------------------
// LuminanceAwareMHSA: B=4, C=256, H=W=48 (N=2304), HEADS=8, DH=32, HID=128
// Round 8:
//   k6: barrier-free per-wave flash attention. K fragments double-buffered
//       global->reg one tile ahead; V loaded at body top (consumed ~400cy
//       later); bias prefetched late (single buffer). No K/V LDS staging,
//       no __syncthreads -> waves drift freely. LDS = 16KB P-scratch only.
//   k5/k7: manual register double-buffering of the kc GEMM loops.
//   k1: 1024 threads (was 256); also zeroes the h1p pad ring -> the
//       hipMemsetAsync dispatch is removed.
// ---------------------------------------------------------------------------

#define NSP 2304
#define WID 48

typedef __attribute__((ext_vector_type(4))) float  fvec4;
typedef __attribute__((ext_vector_type(2))) unsigned int uvec2;
typedef __attribute__((ext_vector_type(4))) unsigned int uvec4;
typedef __attribute__((ext_vector_type(8))) short  short8;   // 8 bf16 (4 VGPRs)
typedef __attribute__((ext_vector_type(4))) float  f32x4;    // MFMA C/D

__device__ inline unsigned short f2bf(float f){
  unsigned int u = __builtin_bit_cast(unsigned int, f);
  u += 0x7fffu + ((u >> 16) & 1u);           // RNE
  return (unsigned short)(u >> 16);
}
__device__ inline unsigned pack2bf(float a, float b){
#if __has_builtin(__builtin_amdgcn_cvt_pk_bf16_f32)
  typedef __attribute__((ext_vector_type(2))) __bf16 bf16x2;
  bf16x2 r = __builtin_amdgcn_cvt_pk_bf16_f32(a, b);
  return __builtin_bit_cast(unsigned, r);
#else
  return (unsigned)f2bf(a) | ((unsigned)f2bf(b) << 16);
#endif
}

// ---------------------------------------------------------------------------
// k0b: cast weights to bf16. idx ranges: [0,147456) wtb, [..,344064) wqkvb,
// [..,409600) wprojb. grid 1600 x 256.
__global__ void k0b_wcast(const float* __restrict__ c2w, const float* __restrict__ wq,
                          const float* __restrict__ wk, const float* __restrict__ wv_,
                          const float* __restrict__ wproj,
                          unsigned short* __restrict__ wtb,
                          unsigned short* __restrict__ wqkvb,
                          unsigned short* __restrict__ wprojb){
  int idx = blockIdx.x*256 + threadIdx.x;
  if (idx < 147456){
    int ic = idx & 127, rem = idx >> 7;
    int oc = rem & 127, tap = rem >> 7;
    wtb[idx] = f2bf(c2w[(oc*128 + ic)*9 + tap]);
  } else if (idx < 344064){
    int j = idx - 147456;
    int mat = j >> 16, oc_ = j & 65535;
    const float* src = (mat == 0) ? wq : (mat == 1) ? wk : wv_;
    wqkvb[j] = f2bf(src[oc_]);
  } else {
    int j = idx - 344064;
    wprojb[j] = f2bf(wproj[j]);
  }
}

// ---------------------------------------------------------------------------
// k0xt: xt[b][n][c] = bf16(x[b][c][n]). grid (36 nt, 4 cc, 4 b), 64n x 64c tile.
__global__ __launch_bounds__(256) void k0xt(const float* __restrict__ x,
                                            unsigned short* __restrict__ xt){
  int nt = blockIdx.x, cc = blockIdx.y, b = blockIdx.z, t = threadIdx.x;
  __shared__ unsigned short tb[64*72];
  int cl0 = t >> 4;           // 0..15
  int nl0 = (t & 15) * 4;     // 0..60
  #pragma unroll
  for (int ps = 0; ps < 4; ++ps){
    int cl = cl0 + ps*16;
    fvec4 v = *(const fvec4*)(x + ((size_t)(b*256 + cc*64 + cl))*NSP + nt*64 + nl0);
    #pragma unroll
    for (int i = 0; i < 4; ++i) tb[(nl0+i)*72 + cl] = f2bf(v[i]);
  }
  __syncthreads();
  int nl = t >> 2, cg = (t & 3) * 16;
  uvec4 u0 = *(const uvec4*)&tb[nl*72 + cg];
  uvec4 u1 = *(const uvec4*)&tb[nl*72 + cg + 8];
  unsigned short* dst = xt + ((size_t)(b*NSP + nt*64 + nl))*256 + cc*64 + cg;
  *(uvec4*)dst = u0;
  *(uvec4*)(dst + 8) = u1;
}

// ---------------------------------------------------------------------------
// K1 (round 8): 1024 threads. luma -> minmax-normalize; 3x3 zero-pad avg-pool
// of (1-luma); mean-center, pre-scale alpha*log2e. Zeros hm_sum AND the h1p
// pad ring (replaces the hipMemsetAsync dispatch).
__global__ __launch_bounds__(1024) void k1_luma(const float* __restrict__ rgb,
                        const float* __restrict__ alphaP,
                        float* __restrict__ luma_n, float* __restrict__ bias_a,
                        float* __restrict__ hm_sum, unsigned short* __restrict__ h1p){
  int b = blockIdx.x, t = threadIdx.x;
  __shared__ float ly[NSP];
  __shared__ float ll[NSP];
  __shared__ float red[1024];
  __shared__ float red2[1024];
  // zero the h1p pad ring (196 ring cells x 128 ch, 16B chunks)
  {
    const uvec4 z = {0u,0u,0u,0u};
    for (int j = t; j < 196*16; j += 1024){
      int cell = j >> 4, q = j & 15;
      int r, c;
      if (cell < 50)      { r = 0;           c = cell; }
      else if (cell < 100){ r = 49;          c = cell - 50; }
      else if (cell < 148){ r = cell - 99;   c = 0; }
      else                { r = cell - 147;  c = 49; }
      *(uvec4*)(h1p + ((size_t)(b*2500 + r*50 + c))*128 + q*8) = z;
    }
  }
  const float* rp = rgb + b*3*NSP;
  float lmin = 1e30f, lmax = -1e30f;
  for (int i = t; i < NSP; i += 1024){
    float y = 0.299f*rp[i] + 0.587f*rp[NSP+i] + 0.114f*rp[2*NSP+i];
    ly[i] = y; lmin = fminf(lmin, y); lmax = fmaxf(lmax, y);
  }
  red[t] = lmin; red2[t] = lmax;
  __syncthreads();
  for (int s = 512; s > 0; s >>= 1){
    if (t < s){ red[t] = fminf(red[t], red[t+s]); red2[t] = fmaxf(red2[t], red2[t+s]); }
    __syncthreads();
  }
  float mn = red[0], mx = red2[0];
  float inv = 1.0f / (mx - mn + 1e-6f);
  for (int i = t; i < NSP; i += 1024){
    float v = (ly[i] - mn) * inv;
    ll[i] = v;
    luma_n[b*NSP + i] = v;
  }
  if (t < 128) hm_sum[b*128 + t] = 0.f;
  __syncthreads();
  float pr[3]; float psum = 0.f;
  #pragma unroll
  for (int ii = 0; ii < 3; ++ii){
    int n = t + 1024*ii;
    pr[ii] = 0.f;
    if (n < NSP){
      int row = n / WID, col = n - row*WID;
      float s = 0.f;
      #pragma unroll
      for (int dy = -1; dy <= 1; ++dy)
        #pragma unroll
        for (int dx = -1; dx <= 1; ++dx){
          int r2 = row+dy, c2 = col+dx;
          if (r2 >= 0 && r2 < WID && c2 >= 0 && c2 < WID) s += 1.0f - ll[r2*WID + c2];
        }
      pr[ii] = s * (1.f/9.f);
      psum += pr[ii];
    }
  }
  __syncthreads();
  red[t] = psum;
  __syncthreads();
  for (int s = 512; s > 0; s >>= 1){
    if (t < s) red[t] += red[t+s];
    __syncthreads();
  }
  float mean = red[0] * (1.f/(float)NSP);
  float alpha = alphaP[0] * 1.4426950408889634f;   // fold log2(e) for exp2
  #pragma unroll
  for (int ii = 0; ii < 3; ++ii){
    int n = t + 1024*ii;
    if (n < NSP) bias_a[b*NSP + n] = alpha * (pr[ii] - mean);
  }
}

// ---------------------------------------------------------------------------
// K2: conv1 3x3, 1 -> 128 channels, relu -> bf16 padded h1p[b][50*50][128].
__global__ void k2_conv1(const float* __restrict__ luma_n, const float* __restrict__ c1w,
                         const float* __restrict__ c1b, unsigned short* __restrict__ h1p){
  int nt = blockIdx.x, ocg = blockIdx.y, b = blockIdx.z, t = threadIdx.x;
  __shared__ float wsm[32*9];
  __shared__ float bsm[32];
  for (int i = t; i < 288; i += 256) wsm[i] = c1w[ocg*288 + i];
  if (t < 32) bsm[t] = c1b[ocg*32 + t];
  __syncthreads();
  int n = nt*256 + t;
  int row = n / WID, col = n - row*WID;
  const float* lp = luma_n + b*NSP;
  float lv[9];
  int k = 0;
  #pragma unroll
  for (int dy = -1; dy <= 1; ++dy)
    #pragma unroll
    for (int dx = -1; dx <= 1; ++dx, ++k){
      int r2 = row+dy, c2 = col+dx;
      lv[k] = (r2 >= 0 && r2 < WID && c2 >= 0 && c2 < WID) ? lp[r2*WID + c2] : 0.f;
    }
  unsigned int packed[16];
  #pragma unroll
  for (int oc2 = 0; oc2 < 16; ++oc2){
    float a0 = bsm[oc2*2], a1 = bsm[oc2*2+1];
    #pragma unroll
    for (int q = 0; q < 9; ++q){
      a0 += wsm[(oc2*2)*9 + q] * lv[q];
      a1 += wsm[(oc2*2+1)*9 + q] * lv[q];
    }
    packed[oc2] = pack2bf(fmaxf(a0, 0.f), fmaxf(a1, 0.f));
  }
  unsigned short* dst = h1p + ((size_t)(b*2500 + (row+1)*50 + (col+1)))*128 + ocg*32;
  #pragma unroll
  for (int q4 = 0; q4 < 4; ++q4)
    *(uvec4*)(dst + q4*8) = *(uvec4*)&packed[q4*4];
}

// ---------------------------------------------------------------------------
// K3: conv2 128->128 as 9 shifted MFMA GEMMs + relu + column-sum -> hm_sum.
__global__ __launch_bounds__(256) void k3_conv2(const unsigned short* __restrict__ h1p,
    const unsigned short* __restrict__ wtb, const float* __restrict__ c2b,
    float* __restrict__ hm_sum){
  int row = blockIdx.x, mh = blockIdx.y, b = blockIdx.z;
  int t = threadIdx.x, wv = t >> 6, lane = t & 63;
  int lq = lane >> 4, lc = lane & 15;
  int ocb = mh*64 + wv*16;
  const f32x4 z4 = {0.f, 0.f, 0.f, 0.f};
  f32x4 C[3] = {z4, z4, z4};
  const unsigned short* hbase = h1p + (size_t)b*2500*128;
  #pragma unroll
  for (int tap = 0; tap < 9; ++tap){
    int dy = tap/3 - 1, dx = tap%3 - 1;
    const unsigned short* wrow = wtb + (tap*128 + ocb + lc)*128 + lq*8;
    const unsigned short* hrow = hbase + ((row+dy+1)*50 + (dx+1) + lc)*128 + lq*8;
    #pragma unroll
    for (int kc = 0; kc < 4; ++kc){
      short8 aW = *(const short8*)(wrow + kc*32);
      #pragma unroll
      for (int ntp = 0; ntp < 3; ++ntp){
        short8 bH = *(const short8*)(hrow + ntp*16*128 + kc*32);
        C[ntp] = __builtin_amdgcn_mfma_f32_16x16x32_bf16(aW, bH, C[ntp], 0, 0, 0);
      }
    }
  }
  float s[4];
  #pragma unroll
  for (int r = 0; r < 4; ++r){
    float bias = c2b[ocb + lq*4 + r];
    float v = 0.f;
    #pragma unroll
    for (int ntp = 0; ntp < 3; ++ntp) v += fmaxf(C[ntp][r] + bias, 0.f);
    v += __shfl_xor(v, 1, 64);
    v += __shfl_xor(v, 2, 64);
    v += __shfl_xor(v, 4, 64);
    v += __shfl_xor(v, 8, 64);
    s[r] = v;
  }
  if (lc == 0){
    #pragma unroll
    for (int r = 0; r < 4; ++r)
      atomicAdd(&hm_sum[b*128 + ocb + lq*4 + r], s[r]);
  }
}

// ---------------------------------------------------------------------------
// K4: FiLM params. film[(m6*4 + b)*256 + o]
__global__ void k4_film(const float* __restrict__ hm_sum,
  const float* w0, const float* b0, const float* w1, const float* b1,
  const float* w2, const float* b2, const float* w3, const float* b3,
  const float* w4, const float* b4, const float* w5, const float* b5,
  float* __restrict__ film){
  __shared__ float hs[128];
  int bb = blockIdx.x & 3, m6 = blockIdx.x >> 2, t = threadIdx.x;
  if (t < 128) hs[t] = hm_sum[bb*128 + t] * (1.f/(float)NSP);
  __syncthreads();
  const float* wm[6] = {w0,w1,w2,w3,w4,w5};
  const float* bm[6] = {b0,b1,b2,b3,b4,b5};
  const float* w = wm[m6];
  int o = t;
  float a = bm[m6][o];
  for (int h2 = 0; h2 < 128; ++h2) a += hs[h2] * w[o*128 + h2];
  film[blockIdx.x*256 + t] = a;
}

// ---------------------------------------------------------------------------
// K5 (round 8): QKV via bf16 MFMA, kc loop register double-buffered.
// grid (36 nt, 6 ot, 4 b); wave: 32 o x 64 n. FiLM epilogue; emits q_t/k_t
// [B,8,N,32] bf16 (SCALE*log2e in q), v_b [B,256,N] bf16.
__global__ __launch_bounds__(256) void k5_qkv(const unsigned short* __restrict__ xt,
    const unsigned short* __restrict__ wqkvb,
    const float* __restrict__ bq, const float* __restrict__ bk, const float* __restrict__ bv,
    const float* __restrict__ film,
    unsigned short* __restrict__ q_t, unsigned short* __restrict__ k_t,
    unsigned short* __restrict__ v_b){
  int nt = blockIdx.x, ot = blockIdx.y, b = blockIdx.z;
  int t = threadIdx.x, wv = t >> 6, lane = t & 63;
  int lq = lane >> 4, lc = lane & 15;
  int p = ot >> 1;
  int omb = (ot & 1)*128 + wv*32;
  const f32x4 z4 = {0.f, 0.f, 0.f, 0.f};
  f32x4 acc[2][4];
  #pragma unroll
  for (int oh = 0; oh < 2; ++oh)
    #pragma unroll
    for (int nq = 0; nq < 4; ++nq) acc[oh][nq] = z4;

  const unsigned short* wbp = wqkvb + p*65536 + (omb + lc)*256 + lq*8;
  const unsigned short* xbp = xt + ((size_t)(b*NSP + nt*64 + lc))*256 + lq*8;

  short8 aW0[2], aW1[2], bX0[4], bX1[4];
  auto loadW = [&](short8 (&W)[2], int kc){
    #pragma unroll
    for (int oh = 0; oh < 2; ++oh) W[oh] = *(const short8*)(wbp + oh*16*256 + kc*32);
  };
  auto loadX = [&](short8 (&X)[4], int kc){
    #pragma unroll
    for (int nq = 0; nq < 4; ++nq) X[nq] = *(const short8*)(xbp + (size_t)nq*16*256 + kc*32);
  };
  auto mm = [&](short8 (&W)[2], short8 (&X)[4]){
    #pragma unroll
    for (int oh = 0; oh < 2; ++oh)
      #pragma unroll
      for (int nq = 0; nq < 4; ++nq)
        acc[oh][nq] = __builtin_amdgcn_mfma_f32_16x16x32_bf16(W[oh], X[nq], acc[oh][nq], 0, 0, 0);
  };
  loadW(aW0, 0); loadX(bX0, 0);
  for (int kc2 = 0; kc2 < 4; ++kc2){
    loadW(aW1, kc2*2+1); loadX(bX1, kc2*2+1);
    mm(aW0, bX0);
    int kn = (kc2*2+2) & 7;          // 8 wraps to 0: harmless warm reload
    loadW(aW0, kn); loadX(bX0, kn);
    mm(aW1, bX1);
  }

  const float* bvec = (p == 0) ? bq : (p == 1) ? bk : bv;
  int hq = omb >> 5;                       // head (uniform per wave), p<2 only
  unsigned short* qk = (p == 0) ? q_t : k_t;
  #pragma unroll
  for (int oh = 0; oh < 2; ++oh){
    fvec4 g4 = *(const fvec4*)(film + (2*p*4 + b)*256 + omb + oh*16 + lq*4);
    fvec4 t4 = *(const fvec4*)(film + ((2*p+1)*4 + b)*256 + omb + oh*16 + lq*4);
    fvec4 z4b = *(const fvec4*)(bvec + omb + oh*16 + lq*4);
    #pragma unroll
    for (int nq = 0; nq < 4; ++nq){
      int n = nt*64 + nq*16 + lc;
      float v0 = g4[0]*(acc[oh][nq][0] + z4b[0]) + t4[0];
      float v1 = g4[1]*(acc[oh][nq][1] + z4b[1]) + t4[1];
      float v2 = g4[2]*(acc[oh][nq][2] + z4b[2]) + t4[2];
      float v3 = g4[3]*(acc[oh][nq][3] + z4b[3]) + t4[3];
      if (p == 0){
        const float sc = 0.17677669529663687f * 1.4426950408889634f;  // SCALE*log2e
        v0 *= sc; v1 *= sc; v2 *= sc; v3 *= sc;
      }
      if (p < 2){
        uvec2 u;
        u.x = pack2bf(v0, v1);
        u.y = pack2bf(v2, v3);
        *(uvec2*)(qk + ((size_t)((b*8 + hq)*NSP + n))*32 + oh*16 + lq*4) = u;
      } else {
        int om = omb + oh*16 + lq*4;
        v_b[((size_t)(b*256 + om + 0))*NSP + n] = f2bf(v0);
        v_b[((size_t)(b*256 + om + 1))*NSP + n] = f2bf(v1);
        v_b[((size_t)(b*256 + om + 2))*NSP + n] = f2bf(v2);
        v_b[((size_t)(b*256 + om + 3))*NSP + n] = f2bf(v3);
      }
    }
  }
}

// ---------------------------------------------------------------------------
// K6 (round 8): barrier-free per-wave flash attention, split-K=2.
// Per wave: 32 queries, 18 x 64-key tiles. K fragments double-buffered
// global->reg one tile ahead; V loaded at body top; bias prefetched late.
// S^T = mfma(A=K, B=Q^T, C=bias); exp2 -> packed bf16 P via per-wave
// swizzled LDS scratch (conflict-free) -> PV + ones-MFMA row-sum.
// Stores bf16 O partials in [B,N,256] (k7 B-frag layout) + f32 l partials.
// grid (36 = 18 qblk x 2 split, 8 h, 4 b).
__global__ __launch_bounds__(256, 4) void k6_attn(const unsigned short* __restrict__ q_t,
    const unsigned short* __restrict__ k_t, const unsigned short* __restrict__ v_b,
    const float* __restrict__ bias_a,
    unsigned short* __restrict__ o0, unsigned short* __restrict__ o1,
    float* __restrict__ l0, float* __restrict__ l1){
  int bx = blockIdx.x, h = blockIdx.y, b = blockIdx.z;
  int qblk = bx >> 1, s = bx & 1;
  unsigned short* op = s ? o1 : o0;
  float* lp = s ? l1 : l0;
  int t = threadIdx.x, wv = t >> 6, lane = t & 63;
  int lq = lane >> 4, lc = lane & 15;
  int bh = b*8 + h;
  int nb0 = qblk*128 + wv*32;
  const f32x4 z4 = {0.f, 0.f, 0.f, 0.f};
  int ms = s*1152;

  __shared__ float ps[4][1024];       // per-wave P scratch (4 KB each)
  float* myps = ps[wv];
  int sxm = ((lc&7)<<2) | (((lc>>3)&1)<<1);  // P scratch dword swizzle
  int wbase = lc*32;

  const unsigned short* kfr = k_t + ((size_t)(bh*NSP + ms + lc))*32 + lq*8;
  const unsigned short* vfr = v_b + ((size_t)(b*256 + h*32 + lc))*NSP + ms + lq*8;
  const float* brow = bias_a + b*NSP + ms;

  short8 aQ[2];
  #pragma unroll
  for (int qf = 0; qf < 2; ++qf)
    aQ[qf] = *(const short8*)(q_t + ((size_t)(bh*NSP + nb0 + qf*16 + lc))*32 + lq*8);

  fvec4 c0r[4];
  #pragma unroll
  for (int g = 0; g < 4; ++g) c0r[g] = *(const fvec4*)(brow + g*16 + lq*4);

  const uvec4 onesu = {0x3F803F80u, 0x3F803F80u, 0x3F803F80u, 0x3F803F80u};
  const short8 aOnes = __builtin_bit_cast(short8, onesu);

  f32x4 O[2][2]; f32x4 Ol[2];
  #pragma unroll
  for (int qf = 0; qf < 2; ++qf){
    Ol[qf] = z4; O[qf][0] = z4; O[qf][1] = z4;
  }

  short8 aKA[4], aKB[4];
  #pragma unroll
  for (int g = 0; g < 4; ++g)
    aKA[g] = *(const short8*)(kfr + (size_t)g*512);

  auto body = [&](short8 (&AK)[4], int it){
    int m0 = it*64;
    // V for this tile: used after S+exp2 phase (~400cy) -> latency hidden
    short8 aV[2][2];
    #pragma unroll
    for (int dhg = 0; dhg < 2; ++dhg)
      #pragma unroll
      for (int mh = 0; mh < 2; ++mh)
        aV[dhg][mh] = *(const short8*)(vfr + (size_t)dhg*16*NSP + m0 + mh*32);
    // S = K.Q^T + bias; exp2; pack; write P scratch
    #pragma unroll
    for (int qf = 0; qf < 2; ++qf){
      #pragma unroll
      for (int g = 0; g < 4; ++g){
        f32x4 S = __builtin_amdgcn_mfma_f32_16x16x32_bf16(AK[g], aQ[qf], c0r[g], 0, 0, 0);
        uvec2 w2;
        w2.x = pack2bf(__builtin_amdgcn_exp2f(S[0]), __builtin_amdgcn_exp2f(S[1]));
        w2.y = pack2bf(__builtin_amdgcn_exp2f(S[2]), __builtin_amdgcn_exp2f(S[3]));
        *(uvec2*)&myps[qf*512 + wbase + ((g*8 + lq*2) ^ sxm)] = w2;
      }
    }
    // prefetch next-tile bias after its last S use
    if (it < 17){
      #pragma unroll
      for (int g = 0; g < 4; ++g)
        c0r[g] = *(const fvec4*)(brow + (it+1)*64 + g*16 + lq*4);
    }
    // PV + row-sum (ones) MFMAs
    __builtin_amdgcn_s_setprio(1);
    #pragma unroll
    for (int qf = 0; qf < 2; ++qf){
      #pragma unroll
      for (int mh = 0; mh < 2; ++mh){
        int d0 = (mh*16 + lq*4) ^ sxm;
        uvec2 lo = *(const uvec2*)&myps[qf*512 + wbase + d0];
        uvec2 hi = *(const uvec2*)&myps[qf*512 + wbase + (d0 ^ 2)];
        uvec4 up; up.x = lo.x; up.y = lo.y; up.z = hi.x; up.w = hi.y;
        short8 bP = __builtin_bit_cast(short8, up);
        Ol[qf] = __builtin_amdgcn_mfma_f32_16x16x32_bf16(aOnes, bP, Ol[qf], 0, 0, 0);
        #pragma unroll
        for (int dhg = 0; dhg < 2; ++dhg)
          O[qf][dhg] = __builtin_amdgcn_mfma_f32_16x16x32_bf16(aV[dhg][mh], bP, O[qf][dhg], 0, 0, 0);
      }
    }
    __builtin_amdgcn_s_setprio(0);
  };

  for (int it2 = 0; it2 < 9; ++it2){
    int it0 = it2*2;
    #pragma unroll
    for (int g = 0; g < 4; ++g)
      aKB[g] = *(const short8*)(kfr + (size_t)(it0+1)*2048 + (size_t)g*512);
    body(aKA, it0);
    // prefetch tile it0+2 (it0+2==18 on last iter: overread lands in the
    // adjacent workspace buffer, values unused)
    #pragma unroll
    for (int g = 0; g < 4; ++g)
      aKA[g] = *(const short8*)(kfr + (size_t)(it0+2)*2048 + (size_t)g*512);
    body(aKB, it0+1);
  }

  // store bf16 O partials [b][n][og] (og = h*32 + d), f32 l partials
  #pragma unroll
  for (int qf = 0; qf < 2; ++qf){
    int nidx = nb0 + qf*16 + lc;
    if (lq == 0) lp[b*NSP + nidx] = Ol[qf][0];
    #pragma unroll
    for (int dh = 0; dh < 2; ++dh){
      uvec2 u;
      u.x = pack2bf(O[qf][dh][0], O[qf][dh][1]);
      u.y = pack2bf(O[qf][dh][2], O[qf][dh][3]);
      *(uvec2*)(op + ((size_t)(b*NSP + nidx))*256 + h*32 + dh*16 + lq*4) = u;
    }
  }
}

// ---------------------------------------------------------------------------
// K7 (round 8): out[c][n] = (sum_o wproj[c][o]*(a0+a1)[o][n]) * rl[n] + bproj[c].
// bf16 MFMA, kc loop register double-buffered; a0/a1 combined through the
// MFMA C chain. grid (72 nt(32 n), 2 ct(128 c), 4 b); wave: 32 c x 32 n.
__global__ __launch_bounds__(256) void k7_proj(const unsigned short* __restrict__ a0,
    const unsigned short* __restrict__ a1, const float* __restrict__ l0p,
    const float* __restrict__ l1p, const unsigned short* __restrict__ wprojb,
    const float* __restrict__ bproj, float* __restrict__ out){
  int nt = blockIdx.x, ct = blockIdx.y, b = blockIdx.z;
  int t = threadIdx.x, wv = t >> 6, lane = t & 63;
  int lq = lane >> 4, lc = lane & 15;
  __shared__ float rls[32];
  if (t < 32) rls[t] = 1.0f / (l0p[b*NSP + nt*32 + t] + l1p[b*NSP + nt*32 + t]);
  __syncthreads();
  int cb = ct*128 + wv*32;
  const f32x4 z4 = {0.f, 0.f, 0.f, 0.f};
  f32x4 acc[2][2];
  #pragma unroll
  for (int ch = 0; ch < 2; ++ch)
    #pragma unroll
    for (int nq = 0; nq < 2; ++nq) acc[ch][nq] = z4;

  const unsigned short* wpp = wprojb + (cb + lc)*256 + lq*8;
  const unsigned short* a0p = a0 + ((size_t)(b*NSP + nt*32 + lc))*256 + lq*8;
  const unsigned short* a1p = a1 + ((size_t)(b*NSP + nt*32 + lc))*256 + lq*8;

  short8 W0[2], W1[2], p00[2], p01[2], p10[2], p11[2];
  auto loadS = [&](short8 (&W)[2], short8 (&B0)[2], short8 (&B1)[2], int kc){
    #pragma unroll
    for (int ch = 0; ch < 2; ++ch) W[ch] = *(const short8*)(wpp + ch*16*256 + kc*32);
    #pragma unroll
    for (int nq = 0; nq < 2; ++nq){
      B0[nq] = *(const short8*)(a0p + (size_t)nq*16*256 + kc*32);
      B1[nq] = *(const short8*)(a1p + (size_t)nq*16*256 + kc*32);
    }
  };
  auto mmS = [&](short8 (&W)[2], short8 (&B0)[2], short8 (&B1)[2]){
    #pragma unroll
    for (int ch = 0; ch < 2; ++ch)
      #pragma unroll
      for (int nq = 0; nq < 2; ++nq){
        acc[ch][nq] = __builtin_amdgcn_mfma_f32_16x16x32_bf16(W[ch], B0[nq], acc[ch][nq], 0, 0, 0);
        acc[ch][nq] = __builtin_amdgcn_mfma_f32_16x16x32_bf16(W[ch], B1[nq], acc[ch][nq], 0, 0, 0);
      }
  };
  loadS(W0, p00, p10, 0);
  for (int kc2 = 0; kc2 < 4; ++kc2){
    loadS(W1, p01, p11, kc2*2+1);
    mmS(W0, p00, p10);
    int kn = (kc2*2+2) & 7;          // 8 wraps to 0: harmless warm reload
    loadS(W0, p00, p10, kn);
    mmS(W1, p01, p11);
  }

  #pragma unroll
  for (int ch = 0; ch < 2; ++ch){
    #pragma unroll
    for (int nq = 0; nq < 2; ++nq){
      int n = nt*32 + nq*16 + lc;
      float rl = rls[nq*16 + lc];
      #pragma unroll
      for (int r = 0; r < 4; ++r){
        int c = cb + ch*16 + lq*4 + r;
        out[((size_t)(b*256 + c))*NSP + n] = acc[ch][nq][r]*rl + bproj[c];
      }
    }
  }
}

// ---------------------------------------------------------------------------
extern "C" void kernel_launch(void* const* d_in, const int* in_sizes, int n_in,
                              void* d_out, int out_size, void* d_ws, size_t ws_size,
                              hipStream_t stream) {
  const float* x     = (const float*)d_in[0];
  const float* rgb   = (const float*)d_in[1];
  const float* wq    = (const float*)d_in[2];
  const float* bq    = (const float*)d_in[3];
  const float* wk    = (const float*)d_in[4];
  const float* bk    = (const float*)d_in[5];
  const float* wv    = (const float*)d_in[6];
  const float* bv    = (const float*)d_in[7];
  const float* wproj = (const float*)d_in[8];
  const float* bproj = (const float*)d_in[9];
  const float* c1w   = (const float*)d_in[10];
  const float* c1b   = (const float*)d_in[11];
  const float* c2w   = (const float*)d_in[12];
  const float* c2b   = (const float*)d_in[13];
  const float* gq_w  = (const float*)d_in[14];
  const float* gq_b  = (const float*)d_in[15];
  const float* bqf_w = (const float*)d_in[16];
  const float* bqf_b = (const float*)d_in[17];
  const float* gk_w  = (const float*)d_in[18];
  const float* gk_b  = (const float*)d_in[19];
  const float* bkf_w = (const float*)d_in[20];
  const float* bkf_b = (const float*)d_in[21];
  const float* gv_w  = (const float*)d_in[22];
  const float* gv_b  = (const float*)d_in[23];
  const float* bvf_w = (const float*)d_in[24];
  const float* bvf_b = (const float*)d_in[25];
  const float* alphaP= (const float*)d_in[26];

  char* w = (char*)d_ws;
  float* luma_n = (float*)w;            w += 4*NSP*4;             // 36864
  float* bias_a = (float*)w;            w += 4*NSP*4;             // 36864
  float* hm_sum = (float*)w;            w += 512*4;               // 2048
  float* film   = (float*)w;            w += 6*4*256*4;           // 24576
  unsigned short* h1p = (unsigned short*)w; w += 4*2500*128*2;    // 2,560,000 (padded bf16)
  unsigned short* wtb = (unsigned short*)w; w += 9*128*128*2;     // 294,912
  unsigned short* wqkvb = (unsigned short*)w; w += 3*256*256*2;   // 393,216
  unsigned short* wprojb = (unsigned short*)w; w += 256*256*2;    // 131,072
  unsigned short* xt  = (unsigned short*)w; w += (size_t)4*NSP*256*2; // 4,718,592
  unsigned short* q_t = (unsigned short*)w; w += (size_t)4*8*NSP*32*2; // 4,718,592
  unsigned short* k_t = (unsigned short*)w; w += (size_t)4*8*NSP*32*2; // 4,718,592
  unsigned short* v_b = (unsigned short*)w; w += (size_t)4*256*NSP*2;  // 4,718,592
  unsigned short* o_part0 = (unsigned short*)w; w += (size_t)4*NSP*256*2; // 4,718,592
  unsigned short* o_part1 = (unsigned short*)w; w += (size_t)4*NSP*256*2; // 4,718,592
  float* l_part0 = (float*)w;           w += 4*NSP*4;             // 36864
  float* l_part1 = (float*)w;           w += 4*NSP*4;             // 36864
  // total ~31.9 MB

  k0b_wcast<<<1600, 256, 0, stream>>>(c2w, wq, wk, wv, wproj, wtb, wqkvb, wprojb);
  k0xt    <<<dim3(36,4,4), 256, 0, stream>>>(x, xt);
  k1_luma <<<4, 1024, 0, stream>>>(rgb, alphaP, luma_n, bias_a, hm_sum, h1p);
  k2_conv1<<<dim3(9,4,4), 256, 0, stream>>>(luma_n, c1w, c1b, h1p);
  k3_conv2<<<dim3(48,2,4), 256, 0, stream>>>(h1p, wtb, c2b, hm_sum);
  k4_film <<<24, 256, 0, stream>>>(hm_sum, gq_w, gq_b, bqf_w, bqf_b,
                                   gk_w, gk_b, bkf_w, bkf_b,
                                   gv_w, gv_b, bvf_w, bvf_b, film);
  k5_qkv  <<<dim3(36,6,4), 256, 0, stream>>>(xt, wqkvb, bq, bk, bv, film,
                                             q_t, k_t, v_b);
  k6_attn <<<dim3(36,8,4), 256, 0, stream>>>(q_t, k_t, v_b, bias_a,
                                             o_part0, o_part1, l_part0, l_part1);
  k7_proj <<<dim3(72,2,4), 256, 0, stream>>>(o_part0, o_part1, l_part0, l_part1,
                                             wprojb, bproj, (float*)d_out);
}

// Round 4
// 277.980 us; speedup vs baseline: 1.0967x; 1.0967x over previous
//
#include <hip/hip_runtime.h>

// ---------------------------------------------------------------------------
// LuminanceAwareMHSA: B=4, C=256, H=W=48 (N=2304), HEADS=8, DH=32, HID=128
// Round 10:
//   k6: round-7 proven staging (reg-stage global->reg, swizzled ds_write,
//       double-buffered LDS, ONE barrier/iter) + round-9's S/PV software
//       pipeline: iter i computes S(i) (MFMA+exp2+pack, VALU-heavy) AND
//       PV(i-1) (pure MFMA on reg-held P(i-1)/V(i-1)) -> independent chains
//       overlap. global_load_lds staging from round 9 REVERTED (correctness
//       failure isolated to it).
//   k5/k7 register double-buffering and k1(1024thr, pad-ring zero) kept.
// ---------------------------------------------------------------------------

#define NSP 2304
#define WID 48

typedef __attribute__((ext_vector_type(4))) float  fvec4;
typedef __attribute__((ext_vector_type(2))) unsigned int uvec2;
typedef __attribute__((ext_vector_type(4))) unsigned int uvec4;
typedef __attribute__((ext_vector_type(8))) short  short8;   // 8 bf16 (4 VGPRs)
typedef __attribute__((ext_vector_type(4))) float  f32x4;    // MFMA C/D

__device__ inline unsigned short f2bf(float f){
  unsigned int u = __builtin_bit_cast(unsigned int, f);
  u += 0x7fffu + ((u >> 16) & 1u);           // RNE
  return (unsigned short)(u >> 16);
}
__device__ inline unsigned pack2bf(float a, float b){
#if __has_builtin(__builtin_amdgcn_cvt_pk_bf16_f32)
  typedef __attribute__((ext_vector_type(2))) __bf16 bf16x2;
  bf16x2 r = __builtin_amdgcn_cvt_pk_bf16_f32(a, b);
  return __builtin_bit_cast(unsigned, r);
#else
  return (unsigned)f2bf(a) | ((unsigned)f2bf(b) << 16);
#endif
}

// ---------------------------------------------------------------------------
// k0b: cast weights to bf16. idx ranges: [0,147456) wtb, [..,344064) wqkvb,
// [..,409600) wprojb. grid 1600 x 256.
__global__ void k0b_wcast(const float* __restrict__ c2w, const float* __restrict__ wq,
                          const float* __restrict__ wk, const float* __restrict__ wv_,
                          const float* __restrict__ wproj,
                          unsigned short* __restrict__ wtb,
                          unsigned short* __restrict__ wqkvb,
                          unsigned short* __restrict__ wprojb){
  int idx = blockIdx.x*256 + threadIdx.x;
  if (idx < 147456){
    int ic = idx & 127, rem = idx >> 7;
    int oc = rem & 127, tap = rem >> 7;
    wtb[idx] = f2bf(c2w[(oc*128 + ic)*9 + tap]);
  } else if (idx < 344064){
    int j = idx - 147456;
    int mat = j >> 16, oc_ = j & 65535;
    const float* src = (mat == 0) ? wq : (mat == 1) ? wk : wv_;
    wqkvb[j] = f2bf(src[oc_]);
  } else {
    int j = idx - 344064;
    wprojb[j] = f2bf(wproj[j]);
  }
}

// ---------------------------------------------------------------------------
// k0xt: xt[b][n][c] = bf16(x[b][c][n]). grid (36 nt, 4 cc, 4 b), 64n x 64c tile.
__global__ __launch_bounds__(256) void k0xt(const float* __restrict__ x,
                                            unsigned short* __restrict__ xt){
  int nt = blockIdx.x, cc = blockIdx.y, b = blockIdx.z, t = threadIdx.x;
  __shared__ unsigned short tb[64*72];
  int cl0 = t >> 4;           // 0..15
  int nl0 = (t & 15) * 4;     // 0..60
  #pragma unroll
  for (int ps = 0; ps < 4; ++ps){
    int cl = cl0 + ps*16;
    fvec4 v = *(const fvec4*)(x + ((size_t)(b*256 + cc*64 + cl))*NSP + nt*64 + nl0);
    #pragma unroll
    for (int i = 0; i < 4; ++i) tb[(nl0+i)*72 + cl] = f2bf(v[i]);
  }
  __syncthreads();
  int nl = t >> 2, cg = (t & 3) * 16;
  uvec4 u0 = *(const uvec4*)&tb[nl*72 + cg];
  uvec4 u1 = *(const uvec4*)&tb[nl*72 + cg + 8];
  unsigned short* dst = xt + ((size_t)(b*NSP + nt*64 + nl))*256 + cc*64 + cg;
  *(uvec4*)dst = u0;
  *(uvec4*)(dst + 8) = u1;
}

// ---------------------------------------------------------------------------
// K1: 1024 threads. luma -> minmax-normalize; 3x3 zero-pad avg-pool of
// (1-luma); mean-center, pre-scale alpha*log2e. Zeros hm_sum AND the h1p
// pad ring (replaces hipMemsetAsync).
__global__ __launch_bounds__(1024) void k1_luma(const float* __restrict__ rgb,
                        const float* __restrict__ alphaP,
                        float* __restrict__ luma_n, float* __restrict__ bias_a,
                        float* __restrict__ hm_sum, unsigned short* __restrict__ h1p){
  int b = blockIdx.x, t = threadIdx.x;
  __shared__ float ly[NSP];
  __shared__ float ll[NSP];
  __shared__ float red[1024];
  __shared__ float red2[1024];
  {
    const uvec4 z = {0u,0u,0u,0u};
    for (int j = t; j < 196*16; j += 1024){
      int cell = j >> 4, q = j & 15;
      int r, c;
      if (cell < 50)      { r = 0;           c = cell; }
      else if (cell < 100){ r = 49;          c = cell - 50; }
      else if (cell < 148){ r = cell - 99;   c = 0; }
      else                { r = cell - 147;  c = 49; }
      *(uvec4*)(h1p + ((size_t)(b*2500 + r*50 + c))*128 + q*8) = z;
    }
  }
  const float* rp = rgb + b*3*NSP;
  float lmin = 1e30f, lmax = -1e30f;
  for (int i = t; i < NSP; i += 1024){
    float y = 0.299f*rp[i] + 0.587f*rp[NSP+i] + 0.114f*rp[2*NSP+i];
    ly[i] = y; lmin = fminf(lmin, y); lmax = fmaxf(lmax, y);
  }
  red[t] = lmin; red2[t] = lmax;
  __syncthreads();
  for (int s = 512; s > 0; s >>= 1){
    if (t < s){ red[t] = fminf(red[t], red[t+s]); red2[t] = fmaxf(red2[t], red2[t+s]); }
    __syncthreads();
  }
  float mn = red[0], mx = red2[0];
  float inv = 1.0f / (mx - mn + 1e-6f);
  for (int i = t; i < NSP; i += 1024){
    float v = (ly[i] - mn) * inv;
    ll[i] = v;
    luma_n[b*NSP + i] = v;
  }
  if (t < 128) hm_sum[b*128 + t] = 0.f;
  __syncthreads();
  float pr[3]; float psum = 0.f;
  #pragma unroll
  for (int ii = 0; ii < 3; ++ii){
    int n = t + 1024*ii;
    pr[ii] = 0.f;
    if (n < NSP){
      int row = n / WID, col = n - row*WID;
      float s = 0.f;
      #pragma unroll
      for (int dy = -1; dy <= 1; ++dy)
        #pragma unroll
        for (int dx = -1; dx <= 1; ++dx){
          int r2 = row+dy, c2 = col+dx;
          if (r2 >= 0 && r2 < WID && c2 >= 0 && c2 < WID) s += 1.0f - ll[r2*WID + c2];
        }
      pr[ii] = s * (1.f/9.f);
      psum += pr[ii];
    }
  }
  __syncthreads();
  red[t] = psum;
  __syncthreads();
  for (int s = 512; s > 0; s >>= 1){
    if (t < s) red[t] += red[t+s];
    __syncthreads();
  }
  float mean = red[0] * (1.f/(float)NSP);
  float alpha = alphaP[0] * 1.4426950408889634f;   // fold log2(e) for exp2
  #pragma unroll
  for (int ii = 0; ii < 3; ++ii){
    int n = t + 1024*ii;
    if (n < NSP) bias_a[b*NSP + n] = alpha * (pr[ii] - mean);
  }
}

// ---------------------------------------------------------------------------
// K2: conv1 3x3, 1 -> 128 channels, relu -> bf16 padded h1p[b][50*50][128].
__global__ void k2_conv1(const float* __restrict__ luma_n, const float* __restrict__ c1w,
                         const float* __restrict__ c1b, unsigned short* __restrict__ h1p){
  int nt = blockIdx.x, ocg = blockIdx.y, b = blockIdx.z, t = threadIdx.x;
  __shared__ float wsm[32*9];
  __shared__ float bsm[32];
  for (int i = t; i < 288; i += 256) wsm[i] = c1w[ocg*288 + i];
  if (t < 32) bsm[t] = c1b[ocg*32 + t];
  __syncthreads();
  int n = nt*256 + t;
  int row = n / WID, col = n - row*WID;
  const float* lp = luma_n + b*NSP;
  float lv[9];
  int k = 0;
  #pragma unroll
  for (int dy = -1; dy <= 1; ++dy)
    #pragma unroll
    for (int dx = -1; dx <= 1; ++dx, ++k){
      int r2 = row+dy, c2 = col+dx;
      lv[k] = (r2 >= 0 && r2 < WID && c2 >= 0 && c2 < WID) ? lp[r2*WID + c2] : 0.f;
    }
  unsigned int packed[16];
  #pragma unroll
  for (int oc2 = 0; oc2 < 16; ++oc2){
    float a0 = bsm[oc2*2], a1 = bsm[oc2*2+1];
    #pragma unroll
    for (int q = 0; q < 9; ++q){
      a0 += wsm[(oc2*2)*9 + q] * lv[q];
      a1 += wsm[(oc2*2+1)*9 + q] * lv[q];
    }
    packed[oc2] = pack2bf(fmaxf(a0, 0.f), fmaxf(a1, 0.f));
  }
  unsigned short* dst = h1p + ((size_t)(b*2500 + (row+1)*50 + (col+1)))*128 + ocg*32;
  #pragma unroll
  for (int q4 = 0; q4 < 4; ++q4)
    *(uvec4*)(dst + q4*8) = *(uvec4*)&packed[q4*4];
}

// ---------------------------------------------------------------------------
// K3: conv2 128->128 as 9 shifted MFMA GEMMs + relu + column-sum -> hm_sum.
__global__ __launch_bounds__(256) void k3_conv2(const unsigned short* __restrict__ h1p,
    const unsigned short* __restrict__ wtb, const float* __restrict__ c2b,
    float* __restrict__ hm_sum){
  int row = blockIdx.x, mh = blockIdx.y, b = blockIdx.z;
  int t = threadIdx.x, wv = t >> 6, lane = t & 63;
  int lq = lane >> 4, lc = lane & 15;
  int ocb = mh*64 + wv*16;
  const f32x4 z4 = {0.f, 0.f, 0.f, 0.f};
  f32x4 C[3] = {z4, z4, z4};
  const unsigned short* hbase = h1p + (size_t)b*2500*128;
  #pragma unroll
  for (int tap = 0; tap < 9; ++tap){
    int dy = tap/3 - 1, dx = tap%3 - 1;
    const unsigned short* wrow = wtb + (tap*128 + ocb + lc)*128 + lq*8;
    const unsigned short* hrow = hbase + ((row+dy+1)*50 + (dx+1) + lc)*128 + lq*8;
    #pragma unroll
    for (int kc = 0; kc < 4; ++kc){
      short8 aW = *(const short8*)(wrow + kc*32);
      #pragma unroll
      for (int ntp = 0; ntp < 3; ++ntp){
        short8 bH = *(const short8*)(hrow + ntp*16*128 + kc*32);
        C[ntp] = __builtin_amdgcn_mfma_f32_16x16x32_bf16(aW, bH, C[ntp], 0, 0, 0);
      }
    }
  }
  float s[4];
  #pragma unroll
  for (int r = 0; r < 4; ++r){
    float bias = c2b[ocb + lq*4 + r];
    float v = 0.f;
    #pragma unroll
    for (int ntp = 0; ntp < 3; ++ntp) v += fmaxf(C[ntp][r] + bias, 0.f);
    v += __shfl_xor(v, 1, 64);
    v += __shfl_xor(v, 2, 64);
    v += __shfl_xor(v, 4, 64);
    v += __shfl_xor(v, 8, 64);
    s[r] = v;
  }
  if (lc == 0){
    #pragma unroll
    for (int r = 0; r < 4; ++r)
      atomicAdd(&hm_sum[b*128 + ocb + lq*4 + r], s[r]);
  }
}

// ---------------------------------------------------------------------------
// K4: FiLM params. film[(m6*4 + b)*256 + o]
__global__ void k4_film(const float* __restrict__ hm_sum,
  const float* w0, const float* b0, const float* w1, const float* b1,
  const float* w2, const float* b2, const float* w3, const float* b3,
  const float* w4, const float* b4, const float* w5, const float* b5,
  float* __restrict__ film){
  __shared__ float hs[128];
  int bb = blockIdx.x & 3, m6 = blockIdx.x >> 2, t = threadIdx.x;
  if (t < 128) hs[t] = hm_sum[bb*128 + t] * (1.f/(float)NSP);
  __syncthreads();
  const float* wm[6] = {w0,w1,w2,w3,w4,w5};
  const float* bm[6] = {b0,b1,b2,b3,b4,b5};
  const float* w = wm[m6];
  int o = t;
  float a = bm[m6][o];
  for (int h2 = 0; h2 < 128; ++h2) a += hs[h2] * w[o*128 + h2];
  film[blockIdx.x*256 + t] = a;
}

// ---------------------------------------------------------------------------
// K5: QKV via bf16 MFMA, kc loop register double-buffered.
// grid (36 nt, 6 ot, 4 b); wave: 32 o x 64 n. FiLM epilogue; emits q_t/k_t
// [B,8,N,32] bf16 (SCALE*log2e in q), v_b [B,256,N] bf16.
__global__ __launch_bounds__(256) void k5_qkv(const unsigned short* __restrict__ xt,
    const unsigned short* __restrict__ wqkvb,
    const float* __restrict__ bq, const float* __restrict__ bk, const float* __restrict__ bv,
    const float* __restrict__ film,
    unsigned short* __restrict__ q_t, unsigned short* __restrict__ k_t,
    unsigned short* __restrict__ v_b){
  int nt = blockIdx.x, ot = blockIdx.y, b = blockIdx.z;
  int t = threadIdx.x, wv = t >> 6, lane = t & 63;
  int lq = lane >> 4, lc = lane & 15;
  int p = ot >> 1;
  int omb = (ot & 1)*128 + wv*32;
  const f32x4 z4 = {0.f, 0.f, 0.f, 0.f};
  f32x4 acc[2][4];
  #pragma unroll
  for (int oh = 0; oh < 2; ++oh)
    #pragma unroll
    for (int nq = 0; nq < 4; ++nq) acc[oh][nq] = z4;

  const unsigned short* wbp = wqkvb + p*65536 + (omb + lc)*256 + lq*8;
  const unsigned short* xbp = xt + ((size_t)(b*NSP + nt*64 + lc))*256 + lq*8;

  short8 aW0[2], aW1[2], bX0[4], bX1[4];
  auto loadW = [&](short8 (&W)[2], int kc){
    #pragma unroll
    for (int oh = 0; oh < 2; ++oh) W[oh] = *(const short8*)(wbp + oh*16*256 + kc*32);
  };
  auto loadX = [&](short8 (&X)[4], int kc){
    #pragma unroll
    for (int nq = 0; nq < 4; ++nq) X[nq] = *(const short8*)(xbp + (size_t)nq*16*256 + kc*32);
  };
  auto mm = [&](short8 (&W)[2], short8 (&X)[4]){
    #pragma unroll
    for (int oh = 0; oh < 2; ++oh)
      #pragma unroll
      for (int nq = 0; nq < 4; ++nq)
        acc[oh][nq] = __builtin_amdgcn_mfma_f32_16x16x32_bf16(W[oh], X[nq], acc[oh][nq], 0, 0, 0);
  };
  loadW(aW0, 0); loadX(bX0, 0);
  for (int kc2 = 0; kc2 < 4; ++kc2){
    loadW(aW1, kc2*2+1); loadX(bX1, kc2*2+1);
    mm(aW0, bX0);
    int kn = (kc2*2+2) & 7;          // 8 wraps to 0: harmless warm reload
    loadW(aW0, kn); loadX(bX0, kn);
    mm(aW1, bX1);
  }

  const float* bvec = (p == 0) ? bq : (p == 1) ? bk : bv;
  int hq = omb >> 5;                       // head (uniform per wave), p<2 only
  unsigned short* qk = (p == 0) ? q_t : k_t;
  #pragma unroll
  for (int oh = 0; oh < 2; ++oh){
    fvec4 g4 = *(const fvec4*)(film + (2*p*4 + b)*256 + omb + oh*16 + lq*4);
    fvec4 t4 = *(const fvec4*)(film + ((2*p+1)*4 + b)*256 + omb + oh*16 + lq*4);
    fvec4 z4b = *(const fvec4*)(bvec + omb + oh*16 + lq*4);
    #pragma unroll
    for (int nq = 0; nq < 4; ++nq){
      int n = nt*64 + nq*16 + lc;
      float v0 = g4[0]*(acc[oh][nq][0] + z4b[0]) + t4[0];
      float v1 = g4[1]*(acc[oh][nq][1] + z4b[1]) + t4[1];
      float v2 = g4[2]*(acc[oh][nq][2] + z4b[2]) + t4[2];
      float v3 = g4[3]*(acc[oh][nq][3] + z4b[3]) + t4[3];
      if (p == 0){
        const float sc = 0.17677669529663687f * 1.4426950408889634f;  // SCALE*log2e
        v0 *= sc; v1 *= sc; v2 *= sc; v3 *= sc;
      }
      if (p < 2){
        uvec2 u;
        u.x = pack2bf(v0, v1);
        u.y = pack2bf(v2, v3);
        *(uvec2*)(qk + ((size_t)((b*8 + hq)*NSP + n))*32 + oh*16 + lq*4) = u;
      } else {
        int om = omb + oh*16 + lq*4;
        v_b[((size_t)(b*256 + om + 0))*NSP + n] = f2bf(v0);
        v_b[((size_t)(b*256 + om + 1))*NSP + n] = f2bf(v1);
        v_b[((size_t)(b*256 + om + 2))*NSP + n] = f2bf(v2);
        v_b[((size_t)(b*256 + om + 3))*NSP + n] = f2bf(v3);
      }
    }
  }
}

// ---------------------------------------------------------------------------
// K6 (round 10): flash attention, split-K=2, block-cooperative staged K/V
// (round-7 proven reg-stage + swizzled ds_write, double-buffered, ONE
// barrier/iter) + S/PV software pipeline: iter it computes S(it) (MFMA+exp2,
// VALU-heavy) and PV(it-1) (pure MFMA on reg-held P(it-1)/V(it-1)).
// P(it-1) is read from per-wave LDS scratch into regs BEFORE sphase
// overwrites it (DS ops are wave-in-order). grid (36=18qblk x 2split, 8h, 4b).
__global__ __launch_bounds__(256, 4) void k6_attn(const unsigned short* __restrict__ q_t,
    const unsigned short* __restrict__ k_t, const unsigned short* __restrict__ v_b,
    const float* __restrict__ bias_a,
    unsigned short* __restrict__ o0, unsigned short* __restrict__ o1,
    float* __restrict__ l0, float* __restrict__ l1){
  int bx = blockIdx.x, h = blockIdx.y, b = blockIdx.z;
  int qblk = bx >> 1, s = bx & 1;
  unsigned short* op = s ? o1 : o0;
  float* lp = s ? l1 : l0;
  int t = threadIdx.x, wv = t >> 6, lane = t & 63;
  int lq = lane >> 4, lc = lane & 15;
  int bh = b*8 + h;
  int nb0 = qblk*128 + wv*32;
  const f32x4 z4 = {0.f, 0.f, 0.f, 0.f};
  int ms = s*1152;

  __shared__ unsigned short Kb[2][64*32];   // [key][dh], slot c holds logical col c^((row>>1)&3)
  __shared__ unsigned short Vb[2][32*64];   // [dh][key], slot c holds logical col c^(row&7)
  __shared__ float ps[4][1024];             // per-wave P scratch
  float* myps = ps[wv];
  int sxm = ((lc&7)<<2) | (((lc>>3)&1)<<1); // P scratch dword swizzle
  int wbase = lc*32;

  // --- staging addresses (16B per thread per tile), round-7 proven ---
  const unsigned short* kg = k_t + ((size_t)(bh*NSP + ms + (t>>2)))*32 + (t&3)*8;
  const unsigned short* vg = v_b + ((size_t)(b*256 + h*32 + (t>>3)))*NSP + ms + (t&7)*8;
  int krow = t >> 2;
  unsigned short* kw = &Kb[0][krow*32 + (((t&3) ^ ((krow>>1)&3))*8)];
  int vrow = t >> 3;
  unsigned short* vw = &Vb[0][vrow*64 + (((t&7) ^ (vrow&7))*8)];

  // fragment read swizzles (round-7 proven)
  int kcol = (lq ^ ((lc>>1)&3))*8;

  const float* brow = bias_a + b*NSP + ms;

  short8 aQ[2];
  #pragma unroll
  for (int qf = 0; qf < 2; ++qf)
    aQ[qf] = *(const short8*)(q_t + ((size_t)(bh*NSP + nb0 + qf*16 + lc))*32 + lq*8);

  fvec4 c0r[4];
  #pragma unroll
  for (int g = 0; g < 4; ++g) c0r[g] = *(const fvec4*)(brow + g*16 + lq*4);

  const uvec4 onesu = {0x3F803F80u, 0x3F803F80u, 0x3F803F80u, 0x3F803F80u};
  const short8 aOnes = __builtin_bit_cast(short8, onesu);

  f32x4 O[2][2]; f32x4 Ol[2];
  #pragma unroll
  for (int qf = 0; qf < 2; ++qf){
    Ol[qf] = z4; O[qf][0] = z4; O[qf][1] = z4;
  }

  short8 aK[4], aV[2][2], bP[2][2];

  auto readP = [&](){
    #pragma unroll
    for (int qf = 0; qf < 2; ++qf)
      #pragma unroll
      for (int mh = 0; mh < 2; ++mh){
        int d0 = (mh*16 + lq*4) ^ sxm;
        uvec2 lo = *(const uvec2*)&myps[qf*512 + wbase + d0];
        uvec2 hi = *(const uvec2*)&myps[qf*512 + wbase + (d0 ^ 2)];
        uvec4 up; up.x = lo.x; up.y = lo.y; up.z = hi.x; up.w = hi.y;
        bP[qf][mh] = __builtin_bit_cast(short8, up);
      }
  };
  auto sphase = [&](){   // S for tile whose K is in aK, bias in c0r -> ps
    #pragma unroll
    for (int qf = 0; qf < 2; ++qf){
      #pragma unroll
      for (int g = 0; g < 4; ++g){
        f32x4 S = __builtin_amdgcn_mfma_f32_16x16x32_bf16(aK[g], aQ[qf], c0r[g], 0, 0, 0);
        uvec2 w2;
        w2.x = pack2bf(__builtin_amdgcn_exp2f(S[0]), __builtin_amdgcn_exp2f(S[1]));
        w2.y = pack2bf(__builtin_amdgcn_exp2f(S[2]), __builtin_amdgcn_exp2f(S[3]));
        *(uvec2*)&myps[qf*512 + wbase + ((g*8 + lq*2) ^ sxm)] = w2;
      }
    }
  };
  auto pv = [&](){       // PV on reg-held bP and aV
    __builtin_amdgcn_s_setprio(1);
    #pragma unroll
    for (int qf = 0; qf < 2; ++qf){
      #pragma unroll
      for (int mh = 0; mh < 2; ++mh){
        Ol[qf] = __builtin_amdgcn_mfma_f32_16x16x32_bf16(aOnes, bP[qf][mh], Ol[qf], 0, 0, 0);
        #pragma unroll
        for (int dhg = 0; dhg < 2; ++dhg)
          O[qf][dhg] = __builtin_amdgcn_mfma_f32_16x16x32_bf16(aV[dhg][mh], bP[qf][mh], O[qf][dhg], 0, 0, 0);
      }
    }
    __builtin_amdgcn_s_setprio(0);
  };

  uvec4 gKr = *(const uvec4*)kg;     // tile 0
  uvec4 gVr = *(const uvec4*)vg;

  for (int it = 0; it < 18; ++it){
    int buf = it & 1;
    // stage tile it into LDS (waits vmcnt on gKr/gVr, loaded last iter)
    *(uvec4*)(kw + buf*2048) = gKr;
    *(uvec4*)(vw + buf*2048) = gVr;
    __syncthreads();
    // issue next-tile loads immediately (consumed by next iter's ds_write)
    if (it < 17){
      gKr = *(const uvec4*)(kg + (size_t)(it+1)*2048);
      gVr = *(const uvec4*)(vg + (it+1)*64);
    }
    // K(it) fragments
    const unsigned short* kb = Kb[buf];
    #pragma unroll
    for (int g = 0; g < 4; ++g)
      aK[g] = *(const short8*)(kb + (g*16 + lc)*32 + kcol);
    if (it > 0) readP();             // P(it-1) -> regs, BEFORE sphase overwrites
    sphase();                        // S(it): MFMA + exp2 + pack + ps writes
    if (it < 17){
      #pragma unroll
      for (int g = 0; g < 4; ++g)
        c0r[g] = *(const fvec4*)(brow + (it+1)*64 + g*16 + lq*4);
    }
    if (it > 0) pv();                // PV(it-1): independent MFMA chain, overlaps exp2
    // V(it) fragments for next iteration's pv (buf intact this iter)
    const unsigned short* vb = Vb[buf];
    #pragma unroll
    for (int dhg = 0; dhg < 2; ++dhg)
      #pragma unroll
      for (int mh = 0; mh < 2; ++mh)
        aV[dhg][mh] = *(const short8*)(vb + (dhg*16 + lc)*64 + (((mh*4 + lq) ^ (lc&7))*8));
  }
  // epilogue: PV(17)
  readP();
  pv();

  // store bf16 O partials [b][n][og] (og = h*32 + d), f32 l partials
  #pragma unroll
  for (int qf = 0; qf < 2; ++qf){
    int nidx = nb0 + qf*16 + lc;
    if (lq == 0) lp[b*NSP + nidx] = Ol[qf][0];
    #pragma unroll
    for (int dh = 0; dh < 2; ++dh){
      uvec2 u;
      u.x = pack2bf(O[qf][dh][0], O[qf][dh][1]);
      u.y = pack2bf(O[qf][dh][2], O[qf][dh][3]);
      *(uvec2*)(op + ((size_t)(b*NSP + nidx))*256 + h*32 + dh*16 + lq*4) = u;
    }
  }
}

// ---------------------------------------------------------------------------
// K7: out[c][n] = (sum_o wproj[c][o]*(a0+a1)[o][n]) * rl[n] + bproj[c].
// bf16 MFMA, kc loop register double-buffered; a0/a1 combined through the
// MFMA C chain. grid (72 nt(32 n), 2 ct(128 c), 4 b); wave: 32 c x 32 n.
__global__ __launch_bounds__(256) void k7_proj(const unsigned short* __restrict__ a0,
    const unsigned short* __restrict__ a1, const float* __restrict__ l0p,
    const float* __restrict__ l1p, const unsigned short* __restrict__ wprojb,
    const float* __restrict__ bproj, float* __restrict__ out){
  int nt = blockIdx.x, ct = blockIdx.y, b = blockIdx.z;
  int t = threadIdx.x, wv = t >> 6, lane = t & 63;
  int lq = lane >> 4, lc = lane & 15;
  __shared__ float rls[32];
  if (t < 32) rls[t] = 1.0f / (l0p[b*NSP + nt*32 + t] + l1p[b*NSP + nt*32 + t]);
  __syncthreads();
  int cb = ct*128 + wv*32;
  const f32x4 z4 = {0.f, 0.f, 0.f, 0.f};
  f32x4 acc[2][2];
  #pragma unroll
  for (int ch = 0; ch < 2; ++ch)
    #pragma unroll
    for (int nq = 0; nq < 2; ++nq) acc[ch][nq] = z4;

  const unsigned short* wpp = wprojb + (cb + lc)*256 + lq*8;
  const unsigned short* a0p = a0 + ((size_t)(b*NSP + nt*32 + lc))*256 + lq*8;
  const unsigned short* a1p = a1 + ((size_t)(b*NSP + nt*32 + lc))*256 + lq*8;

  short8 W0[2], W1[2], p00[2], p01[2], p10[2], p11[2];
  auto loadS = [&](short8 (&W)[2], short8 (&B0)[2], short8 (&B1)[2], int kc){
    #pragma unroll
    for (int ch = 0; ch < 2; ++ch) W[ch] = *(const short8*)(wpp + ch*16*256 + kc*32);
    #pragma unroll
    for (int nq = 0; nq < 2; ++nq){
      B0[nq] = *(const short8*)(a0p + (size_t)nq*16*256 + kc*32);
      B1[nq] = *(const short8*)(a1p + (size_t)nq*16*256 + kc*32);
    }
  };
  auto mmS = [&](short8 (&W)[2], short8 (&B0)[2], short8 (&B1)[2]){
    #pragma unroll
    for (int ch = 0; ch < 2; ++ch)
      #pragma unroll
      for (int nq = 0; nq < 2; ++nq){
        acc[ch][nq] = __builtin_amdgcn_mfma_f32_16x16x32_bf16(W[ch], B0[nq], acc[ch][nq], 0, 0, 0);
        acc[ch][nq] = __builtin_amdgcn_mfma_f32_16x16x32_bf16(W[ch], B1[nq], acc[ch][nq], 0, 0, 0);
      }
  };
  loadS(W0, p00, p10, 0);
  for (int kc2 = 0; kc2 < 4; ++kc2){
    loadS(W1, p01, p11, kc2*2+1);
    mmS(W0, p00, p10);
    int kn = (kc2*2+2) & 7;          // 8 wraps to 0: harmless warm reload
    loadS(W0, p00, p10, kn);
    mmS(W1, p01, p11);
  }

  #pragma unroll
  for (int ch = 0; ch < 2; ++ch){
    #pragma unroll
    for (int nq = 0; nq < 2; ++nq){
      int n = nt*32 + nq*16 + lc;
      float rl = rls[nq*16 + lc];
      #pragma unroll
      for (int r = 0; r < 4; ++r){
        int c = cb + ch*16 + lq*4 + r;
        out[((size_t)(b*256 + c))*NSP + n] = acc[ch][nq][r]*rl + bproj[c];
      }
    }
  }
}

// ---------------------------------------------------------------------------
extern "C" void kernel_launch(void* const* d_in, const int* in_sizes, int n_in,
                              void* d_out, int out_size, void* d_ws, size_t ws_size,
                              hipStream_t stream) {
  const float* x     = (const float*)d_in[0];
  const float* rgb   = (const float*)d_in[1];
  const float* wq    = (const float*)d_in[2];
  const float* bq    = (const float*)d_in[3];
  const float* wk    = (const float*)d_in[4];
  const float* bk    = (const float*)d_in[5];
  const float* wv    = (const float*)d_in[6];
  const float* bv    = (const float*)d_in[7];
  const float* wproj = (const float*)d_in[8];
  const float* bproj = (const float*)d_in[9];
  const float* c1w   = (const float*)d_in[10];
  const float* c1b   = (const float*)d_in[11];
  const float* c2w   = (const float*)d_in[12];
  const float* c2b   = (const float*)d_in[13];
  const float* gq_w  = (const float*)d_in[14];
  const float* gq_b  = (const float*)d_in[15];
  const float* bqf_w = (const float*)d_in[16];
  const float* bqf_b = (const float*)d_in[17];
  const float* gk_w  = (const float*)d_in[18];
  const float* gk_b  = (const float*)d_in[19];
  const float* bkf_w = (const float*)d_in[20];
  const float* bkf_b = (const float*)d_in[21];
  const float* gv_w  = (const float*)d_in[22];
  const float* gv_b  = (const float*)d_in[23];
  const float* bvf_w = (const float*)d_in[24];
  const float* bvf_b = (const float*)d_in[25];
  const float* alphaP= (const float*)d_in[26];

  char* w = (char*)d_ws;
  float* luma_n = (float*)w;            w += 4*NSP*4;             // 36864
  float* bias_a = (float*)w;            w += 4*NSP*4;             // 36864
  float* hm_sum = (float*)w;            w += 512*4;               // 2048
  float* film   = (float*)w;            w += 6*4*256*4;           // 24576
  unsigned short* h1p = (unsigned short*)w; w += 4*2500*128*2;    // 2,560,000 (padded bf16)
  unsigned short* wtb = (unsigned short*)w; w += 9*128*128*2;     // 294,912
  unsigned short* wqkvb = (unsigned short*)w; w += 3*256*256*2;   // 393,216
  unsigned short* wprojb = (unsigned short*)w; w += 256*256*2;    // 131,072
  unsigned short* xt  = (unsigned short*)w; w += (size_t)4*NSP*256*2; // 4,718,592
  unsigned short* q_t = (unsigned short*)w; w += (size_t)4*8*NSP*32*2; // 4,718,592
  unsigned short* k_t = (unsigned short*)w; w += (size_t)4*8*NSP*32*2; // 4,718,592
  unsigned short* v_b = (unsigned short*)w; w += (size_t)4*256*NSP*2;  // 4,718,592
  unsigned short* o_part0 = (unsigned short*)w; w += (size_t)4*NSP*256*2; // 4,718,592
  unsigned short* o_part1 = (unsigned short*)w; w += (size_t)4*NSP*256*2; // 4,718,592
  float* l_part0 = (float*)w;           w += 4*NSP*4;             // 36864
  float* l_part1 = (float*)w;           w += 4*NSP*4;             // 36864
  // total ~31.9 MB

  k0b_wcast<<<1600, 256, 0, stream>>>(c2w, wq, wk, wv, wproj, wtb, wqkvb, wprojb);
  k0xt    <<<dim3(36,4,4), 256, 0, stream>>>(x, xt);
  k1_luma <<<4, 1024, 0, stream>>>(rgb, alphaP, luma_n, bias_a, hm_sum, h1p);
  k2_conv1<<<dim3(9,4,4), 256, 0, stream>>>(luma_n, c1w, c1b, h1p);
  k3_conv2<<<dim3(48,2,4), 256, 0, stream>>>(h1p, wtb, c2b, hm_sum);
  k4_film <<<24, 256, 0, stream>>>(hm_sum, gq_w, gq_b, bqf_w, bqf_b,
                                   gk_w, gk_b, bkf_w, bkf_b,
                                   gv_w, gv_b, bvf_w, bvf_b, film);
  k5_qkv  <<<dim3(36,6,4), 256, 0, stream>>>(xt, wqkvb, bq, bk, bv, film,
                                             q_t, k_t, v_b);
  k6_attn <<<dim3(36,8,4), 256, 0, stream>>>(q_t, k_t, v_b, bias_a,
                                             o_part0, o_part1, l_part0, l_part1);
  k7_proj <<<dim3(72,2,4), 256, 0, stream>>>(o_part0, o_part1, l_part0, l_part1,
                                             wprojb, bproj, (float*)d_out);
}

// Round 5
// 259.731 us; speedup vs baseline: 1.1737x; 1.0703x over previous
//
#include <hip/hip_runtime.h>

// ---------------------------------------------------------------------------
// LuminanceAwareMHSA: B=4, C=256, H=W=48 (N=2304), HEADS=8, DH=32, HID=128
// Round 11 (consolidation):
//   k6: reverted VERBATIM to the round-7 kernel (measured 53.4us, passed).
//       Round-10's S/PV pipeline spilled to scratch (VGPR capped 64 by
//       launch_bounds(256,4); FETCH+WRITE grew +16.5MB) -> reverted.
//   k_prep: k0b + k0xt + k1 fused into ONE dispatch (independent jobs,
//       block-uniform branch on blockIdx.x; luma blocks first). 9->7 launches.
//   k5/k7 register double-buffering kept (passing since R8).
// ---------------------------------------------------------------------------

#define NSP 2304
#define WID 48

typedef __attribute__((ext_vector_type(4))) float  fvec4;
typedef __attribute__((ext_vector_type(2))) unsigned int uvec2;
typedef __attribute__((ext_vector_type(4))) unsigned int uvec4;
typedef __attribute__((ext_vector_type(8))) short  short8;   // 8 bf16 (4 VGPRs)
typedef __attribute__((ext_vector_type(4))) float  f32x4;    // MFMA C/D

__device__ inline unsigned short f2bf(float f){
  unsigned int u = __builtin_bit_cast(unsigned int, f);
  u += 0x7fffu + ((u >> 16) & 1u);           // RNE
  return (unsigned short)(u >> 16);
}
__device__ inline unsigned pack2bf(float a, float b){
#if __has_builtin(__builtin_amdgcn_cvt_pk_bf16_f32)
  typedef __attribute__((ext_vector_type(2))) __bf16 bf16x2;
  bf16x2 r = __builtin_amdgcn_cvt_pk_bf16_f32(a, b);
  return __builtin_bit_cast(unsigned, r);
#else
  return (unsigned)f2bf(a) | ((unsigned)f2bf(b) << 16);
#endif
}

// ---------------------------------------------------------------------------
// k_prep: fused prep. blockIdx.x ranges:
//   [0,4)       : k1 luma job (b = bx) - minmax norm, pooled bias, hm_sum zero,
//                 h1p pad-ring zero
//   [4,1604)    : weight cast job (idx = (bx-4)*256+t), ranges as before:
//                 [0,147456) wtb, [..,344064) wqkvb, [..,409600) wprojb
//   [1604,2180) : xt transpose job (flat j = bx-1604 -> nt,cc,b)
// Shared-memory union: k1 needs 20480B, xt needs 9216B.
__global__ __launch_bounds__(256) void k_prep(const float* __restrict__ c2w,
    const float* __restrict__ wq, const float* __restrict__ wk, const float* __restrict__ wv_,
    const float* __restrict__ wproj, const float* __restrict__ x,
    const float* __restrict__ rgb, const float* __restrict__ alphaP,
    unsigned short* __restrict__ wtb, unsigned short* __restrict__ wqkvb,
    unsigned short* __restrict__ wprojb, unsigned short* __restrict__ xt,
    float* __restrict__ luma_n, float* __restrict__ bias_a,
    float* __restrict__ hm_sum, unsigned short* __restrict__ h1p){
  __shared__ __align__(16) float sm[5120];   // 20480 B union
  int bx = blockIdx.x, t = threadIdx.x;
  if (bx < 4){
    // ---------------- k1 luma job ----------------
    int b = bx;
    float* ly  = sm;
    float* ll  = sm + NSP;
    float* red = sm + 2*NSP;
    float* red2= sm + 2*NSP + 256;
    {
      const uvec4 z = {0u,0u,0u,0u};
      for (int j = t; j < 196*16; j += 256){
        int cell = j >> 4, q = j & 15;
        int r, c;
        if (cell < 50)      { r = 0;           c = cell; }
        else if (cell < 100){ r = 49;          c = cell - 50; }
        else if (cell < 148){ r = cell - 99;   c = 0; }
        else                { r = cell - 147;  c = 49; }
        *(uvec4*)(h1p + ((size_t)(b*2500 + r*50 + c))*128 + q*8) = z;
      }
    }
    const float* rp = rgb + b*3*NSP;
    float lmin = 1e30f, lmax = -1e30f;
    for (int i = t; i < NSP; i += 256){
      float y = 0.299f*rp[i] + 0.587f*rp[NSP+i] + 0.114f*rp[2*NSP+i];
      ly[i] = y; lmin = fminf(lmin, y); lmax = fmaxf(lmax, y);
    }
    red[t] = lmin; red2[t] = lmax;
    __syncthreads();
    for (int s = 128; s > 0; s >>= 1){
      if (t < s){ red[t] = fminf(red[t], red[t+s]); red2[t] = fmaxf(red2[t], red2[t+s]); }
      __syncthreads();
    }
    float mn = red[0], mx = red2[0];
    float inv = 1.0f / (mx - mn + 1e-6f);
    for (int i = t; i < NSP; i += 256){
      float v = (ly[i] - mn) * inv;
      ll[i] = v;
      luma_n[b*NSP + i] = v;
    }
    if (t < 128) hm_sum[b*128 + t] = 0.f;
    __syncthreads();
    float pr[9]; float psum = 0.f;
    #pragma unroll
    for (int ii = 0; ii < 9; ++ii){
      int n = t + 256*ii;
      int row = n / WID, col = n - row*WID;
      float s2 = 0.f;
      #pragma unroll
      for (int dy = -1; dy <= 1; ++dy)
        #pragma unroll
        for (int dx = -1; dx <= 1; ++dx){
          int r2 = row+dy, c2 = col+dx;
          if (r2 >= 0 && r2 < WID && c2 >= 0 && c2 < WID) s2 += 1.0f - ll[r2*WID + c2];
        }
      pr[ii] = s2 * (1.f/9.f);
      psum += pr[ii];
    }
    __syncthreads();
    red[t] = psum;
    __syncthreads();
    for (int s = 128; s > 0; s >>= 1){
      if (t < s) red[t] += red[t+s];
      __syncthreads();
    }
    float mean = red[0] * (1.f/(float)NSP);
    float alpha = alphaP[0] * 1.4426950408889634f;   // fold log2(e) for exp2
    #pragma unroll
    for (int ii = 0; ii < 9; ++ii){
      int n = t + 256*ii;
      bias_a[b*NSP + n] = alpha * (pr[ii] - mean);
    }
  } else if (bx < 1604){
    // ---------------- weight cast job ----------------
    int idx = (bx - 4)*256 + t;
    if (idx < 147456){
      int ic = idx & 127, rem = idx >> 7;
      int oc = rem & 127, tap = rem >> 7;
      wtb[idx] = f2bf(c2w[(oc*128 + ic)*9 + tap]);
    } else if (idx < 344064){
      int j = idx - 147456;
      int mat = j >> 16, oc_ = j & 65535;
      const float* src = (mat == 0) ? wq : (mat == 1) ? wk : wv_;
      wqkvb[j] = f2bf(src[oc_]);
    } else {
      int j = idx - 344064;
      wprojb[j] = f2bf(wproj[j]);
    }
  } else {
    // ---------------- xt transpose job ----------------
    int j = bx - 1604;                 // 0..575
    int nt = j % 36, cc = (j / 36) & 3, b = j / 144;
    unsigned short* tb = (unsigned short*)sm;   // 64*72 shorts = 9216 B
    int cl0 = t >> 4;           // 0..15
    int nl0 = (t & 15) * 4;     // 0..60
    #pragma unroll
    for (int ps_ = 0; ps_ < 4; ++ps_){
      int cl = cl0 + ps_*16;
      fvec4 v = *(const fvec4*)(x + ((size_t)(b*256 + cc*64 + cl))*NSP + nt*64 + nl0);
      #pragma unroll
      for (int i = 0; i < 4; ++i) tb[(nl0+i)*72 + cl] = f2bf(v[i]);
    }
    __syncthreads();
    int nl = t >> 2, cg = (t & 3) * 16;
    uvec4 u0 = *(const uvec4*)&tb[nl*72 + cg];
    uvec4 u1 = *(const uvec4*)&tb[nl*72 + cg + 8];
    unsigned short* dst = xt + ((size_t)(b*NSP + nt*64 + nl))*256 + cc*64 + cg;
    *(uvec4*)dst = u0;
    *(uvec4*)(dst + 8) = u1;
  }
}

// ---------------------------------------------------------------------------
// K2: conv1 3x3, 1 -> 128 channels, relu -> bf16 padded h1p[b][50*50][128].
__global__ void k2_conv1(const float* __restrict__ luma_n, const float* __restrict__ c1w,
                         const float* __restrict__ c1b, unsigned short* __restrict__ h1p){
  int nt = blockIdx.x, ocg = blockIdx.y, b = blockIdx.z, t = threadIdx.x;
  __shared__ float wsm[32*9];
  __shared__ float bsm[32];
  for (int i = t; i < 288; i += 256) wsm[i] = c1w[ocg*288 + i];
  if (t < 32) bsm[t] = c1b[ocg*32 + t];
  __syncthreads();
  int n = nt*256 + t;
  int row = n / WID, col = n - row*WID;
  const float* lp = luma_n + b*NSP;
  float lv[9];
  int k = 0;
  #pragma unroll
  for (int dy = -1; dy <= 1; ++dy)
    #pragma unroll
    for (int dx = -1; dx <= 1; ++dx, ++k){
      int r2 = row+dy, c2 = col+dx;
      lv[k] = (r2 >= 0 && r2 < WID && c2 >= 0 && c2 < WID) ? lp[r2*WID + c2] : 0.f;
    }
  unsigned int packed[16];
  #pragma unroll
  for (int oc2 = 0; oc2 < 16; ++oc2){
    float a0 = bsm[oc2*2], a1 = bsm[oc2*2+1];
    #pragma unroll
    for (int q = 0; q < 9; ++q){
      a0 += wsm[(oc2*2)*9 + q] * lv[q];
      a1 += wsm[(oc2*2+1)*9 + q] * lv[q];
    }
    packed[oc2] = pack2bf(fmaxf(a0, 0.f), fmaxf(a1, 0.f));
  }
  unsigned short* dst = h1p + ((size_t)(b*2500 + (row+1)*50 + (col+1)))*128 + ocg*32;
  #pragma unroll
  for (int q4 = 0; q4 < 4; ++q4)
    *(uvec4*)(dst + q4*8) = *(uvec4*)&packed[q4*4];
}

// ---------------------------------------------------------------------------
// K3: conv2 128->128 as 9 shifted MFMA GEMMs + relu + column-sum -> hm_sum.
__global__ __launch_bounds__(256) void k3_conv2(const unsigned short* __restrict__ h1p,
    const unsigned short* __restrict__ wtb, const float* __restrict__ c2b,
    float* __restrict__ hm_sum){
  int row = blockIdx.x, mh = blockIdx.y, b = blockIdx.z;
  int t = threadIdx.x, wv = t >> 6, lane = t & 63;
  int lq = lane >> 4, lc = lane & 15;
  int ocb = mh*64 + wv*16;
  const f32x4 z4 = {0.f, 0.f, 0.f, 0.f};
  f32x4 C[3] = {z4, z4, z4};
  const unsigned short* hbase = h1p + (size_t)b*2500*128;
  #pragma unroll
  for (int tap = 0; tap < 9; ++tap){
    int dy = tap/3 - 1, dx = tap%3 - 1;
    const unsigned short* wrow = wtb + (tap*128 + ocb + lc)*128 + lq*8;
    const unsigned short* hrow = hbase + ((row+dy+1)*50 + (dx+1) + lc)*128 + lq*8;
    #pragma unroll
    for (int kc = 0; kc < 4; ++kc){
      short8 aW = *(const short8*)(wrow + kc*32);
      #pragma unroll
      for (int ntp = 0; ntp < 3; ++ntp){
        short8 bH = *(const short8*)(hrow + ntp*16*128 + kc*32);
        C[ntp] = __builtin_amdgcn_mfma_f32_16x16x32_bf16(aW, bH, C[ntp], 0, 0, 0);
      }
    }
  }
  float s[4];
  #pragma unroll
  for (int r = 0; r < 4; ++r){
    float bias = c2b[ocb + lq*4 + r];
    float v = 0.f;
    #pragma unroll
    for (int ntp = 0; ntp < 3; ++ntp) v += fmaxf(C[ntp][r] + bias, 0.f);
    v += __shfl_xor(v, 1, 64);
    v += __shfl_xor(v, 2, 64);
    v += __shfl_xor(v, 4, 64);
    v += __shfl_xor(v, 8, 64);
    s[r] = v;
  }
  if (lc == 0){
    #pragma unroll
    for (int r = 0; r < 4; ++r)
      atomicAdd(&hm_sum[b*128 + ocb + lq*4 + r], s[r]);
  }
}

// ---------------------------------------------------------------------------
// K4: FiLM params. film[(m6*4 + b)*256 + o]
__global__ void k4_film(const float* __restrict__ hm_sum,
  const float* w0, const float* b0, const float* w1, const float* b1,
  const float* w2, const float* b2, const float* w3, const float* b3,
  const float* w4, const float* b4, const float* w5, const float* b5,
  float* __restrict__ film){
  __shared__ float hs[128];
  int bb = blockIdx.x & 3, m6 = blockIdx.x >> 2, t = threadIdx.x;
  if (t < 128) hs[t] = hm_sum[bb*128 + t] * (1.f/(float)NSP);
  __syncthreads();
  const float* wm[6] = {w0,w1,w2,w3,w4,w5};
  const float* bm[6] = {b0,b1,b2,b3,b4,b5};
  const float* w = wm[m6];
  int o = t;
  float a = bm[m6][o];
  for (int h2 = 0; h2 < 128; ++h2) a += hs[h2] * w[o*128 + h2];
  film[blockIdx.x*256 + t] = a;
}

// ---------------------------------------------------------------------------
// K5: QKV via bf16 MFMA, kc loop register double-buffered.
// grid (36 nt, 6 ot, 4 b); wave: 32 o x 64 n. FiLM epilogue; emits q_t/k_t
// [B,8,N,32] bf16 (SCALE*log2e in q), v_b [B,256,N] bf16.
__global__ __launch_bounds__(256) void k5_qkv(const unsigned short* __restrict__ xt,
    const unsigned short* __restrict__ wqkvb,
    const float* __restrict__ bq, const float* __restrict__ bk, const float* __restrict__ bv,
    const float* __restrict__ film,
    unsigned short* __restrict__ q_t, unsigned short* __restrict__ k_t,
    unsigned short* __restrict__ v_b){
  int nt = blockIdx.x, ot = blockIdx.y, b = blockIdx.z;
  int t = threadIdx.x, wv = t >> 6, lane = t & 63;
  int lq = lane >> 4, lc = lane & 15;
  int p = ot >> 1;
  int omb = (ot & 1)*128 + wv*32;
  const f32x4 z4 = {0.f, 0.f, 0.f, 0.f};
  f32x4 acc[2][4];
  #pragma unroll
  for (int oh = 0; oh < 2; ++oh)
    #pragma unroll
    for (int nq = 0; nq < 4; ++nq) acc[oh][nq] = z4;

  const unsigned short* wbp = wqkvb + p*65536 + (omb + lc)*256 + lq*8;
  const unsigned short* xbp = xt + ((size_t)(b*NSP + nt*64 + lc))*256 + lq*8;

  short8 aW0[2], aW1[2], bX0[4], bX1[4];
  auto loadW = [&](short8 (&W)[2], int kc){
    #pragma unroll
    for (int oh = 0; oh < 2; ++oh) W[oh] = *(const short8*)(wbp + oh*16*256 + kc*32);
  };
  auto loadX = [&](short8 (&X)[4], int kc){
    #pragma unroll
    for (int nq = 0; nq < 4; ++nq) X[nq] = *(const short8*)(xbp + (size_t)nq*16*256 + kc*32);
  };
  auto mm = [&](short8 (&W)[2], short8 (&X)[4]){
    #pragma unroll
    for (int oh = 0; oh < 2; ++oh)
      #pragma unroll
      for (int nq = 0; nq < 4; ++nq)
        acc[oh][nq] = __builtin_amdgcn_mfma_f32_16x16x32_bf16(W[oh], X[nq], acc[oh][nq], 0, 0, 0);
  };
  loadW(aW0, 0); loadX(bX0, 0);
  for (int kc2 = 0; kc2 < 4; ++kc2){
    loadW(aW1, kc2*2+1); loadX(bX1, kc2*2+1);
    mm(aW0, bX0);
    int kn = (kc2*2+2) & 7;          // 8 wraps to 0: harmless warm reload
    loadW(aW0, kn); loadX(bX0, kn);
    mm(aW1, bX1);
  }

  const float* bvec = (p == 0) ? bq : (p == 1) ? bk : bv;
  int hq = omb >> 5;                       // head (uniform per wave), p<2 only
  unsigned short* qk = (p == 0) ? q_t : k_t;
  #pragma unroll
  for (int oh = 0; oh < 2; ++oh){
    fvec4 g4 = *(const fvec4*)(film + (2*p*4 + b)*256 + omb + oh*16 + lq*4);
    fvec4 t4 = *(const fvec4*)(film + ((2*p+1)*4 + b)*256 + omb + oh*16 + lq*4);
    fvec4 z4b = *(const fvec4*)(bvec + omb + oh*16 + lq*4);
    #pragma unroll
    for (int nq = 0; nq < 4; ++nq){
      int n = nt*64 + nq*16 + lc;
      float v0 = g4[0]*(acc[oh][nq][0] + z4b[0]) + t4[0];
      float v1 = g4[1]*(acc[oh][nq][1] + z4b[1]) + t4[1];
      float v2 = g4[2]*(acc[oh][nq][2] + z4b[2]) + t4[2];
      float v3 = g4[3]*(acc[oh][nq][3] + z4b[3]) + t4[3];
      if (p == 0){
        const float sc = 0.17677669529663687f * 1.4426950408889634f;  // SCALE*log2e
        v0 *= sc; v1 *= sc; v2 *= sc; v3 *= sc;
      }
      if (p < 2){
        uvec2 u;
        u.x = pack2bf(v0, v1);
        u.y = pack2bf(v2, v3);
        *(uvec2*)(qk + ((size_t)((b*8 + hq)*NSP + n))*32 + oh*16 + lq*4) = u;
      } else {
        int om = omb + oh*16 + lq*4;
        v_b[((size_t)(b*256 + om + 0))*NSP + n] = f2bf(v0);
        v_b[((size_t)(b*256 + om + 1))*NSP + n] = f2bf(v1);
        v_b[((size_t)(b*256 + om + 2))*NSP + n] = f2bf(v2);
        v_b[((size_t)(b*256 + om + 3))*NSP + n] = f2bf(v3);
      }
    }
  }
}

// ---------------------------------------------------------------------------
// K6 (round 7, verbatim - measured 53.4us): flash attention, split-K=2,
// block-cooperative staged K/V. Per block: 4 waves x 32 queries; 18 iters of
// 64-key tiles. Reg-stage 16B/thread into double-buffered swizzled LDS, ONE
// __syncthreads per iter; next-tile global loads issued right after the
// barrier. S^T = mfma(A=Kfrag, B=Q^T, C=bias); exp2 -> packed bf16 P in
// per-wave swizzled scratch -> PV + ones MFMAs. grid (36, 8, 4).
__global__ __launch_bounds__(256, 4) void k6_attn(const unsigned short* __restrict__ q_t,
    const unsigned short* __restrict__ k_t, const unsigned short* __restrict__ v_b,
    const float* __restrict__ bias_a,
    unsigned short* __restrict__ o0, unsigned short* __restrict__ o1,
    float* __restrict__ l0, float* __restrict__ l1){
  int bx = blockIdx.x, h = blockIdx.y, b = blockIdx.z;
  int qblk = bx >> 1, s = bx & 1;
  unsigned short* op = s ? o1 : o0;
  float* lp = s ? l1 : l0;
  int t = threadIdx.x, wv = t >> 6, lane = t & 63;
  int lq = lane >> 4, lc = lane & 15;
  int bh = b*8 + h;
  int nb0 = qblk*128 + wv*32;
  const f32x4 z4 = {0.f, 0.f, 0.f, 0.f};
  int ms = s*1152;

  __shared__ unsigned short Kb[2][64*32];   // [key][dh], 16B col c stored at c^((row>>1)&3)
  __shared__ unsigned short Vb[2][32*64];   // [dh][key], 16B col c stored at c^(row&7)
  __shared__ float ps[4][1024];             // per-wave P scratch, 2 qf regions of 16x32 dwords

  // --- staging addresses (16B per thread per tile) ---
  const unsigned short* kg = k_t + ((size_t)bh*NSP + ms + (t>>2))*32 + (t&3)*8;
  const unsigned short* vg = v_b + ((size_t)(b*256 + h*32 + (t>>3)))*NSP + ms + (t&7)*8;
  int krow = t >> 2;
  unsigned short* kw = &Kb[0][krow*32 + (((t&3) ^ ((krow>>1)&3))*8)];
  int vrow = t >> 3;
  unsigned short* vw = &Vb[0][vrow*64 + (((t&7) ^ (vrow&7))*8)];

  // --- per-wave fragment read offsets (swizzled) ---
  int kcol = (lq ^ ((lc>>1)&3))*8;        // Kb col slot for aK
  int sxm = ((lc&7)<<2) | (((lc>>3)&1)<<1);  // P scratch dword swizzle
  int wbase = lc*32;

  const float* brow = bias_a + b*NSP + ms;
  fvec4 c0r[4];
  #pragma unroll
  for (int g = 0; g < 4; ++g) c0r[g] = *(const fvec4*)(brow + g*16 + lq*4);

  short8 aQ[2];
  #pragma unroll
  for (int qf = 0; qf < 2; ++qf)
    aQ[qf] = *(const short8*)(q_t + ((size_t)(bh*NSP + nb0 + qf*16 + lc))*32 + lq*8);

  uvec4 gKr = *(const uvec4*)kg;
  uvec4 gVr = *(const uvec4*)vg;

  const uvec4 onesu = {0x3F803F80u, 0x3F803F80u, 0x3F803F80u, 0x3F803F80u};
  const short8 aOnes = __builtin_bit_cast(short8, onesu);

  f32x4 O[2][2]; f32x4 Ol[2];
  #pragma unroll
  for (int qf = 0; qf < 2; ++qf){
    Ol[qf] = z4; O[qf][0] = z4; O[qf][1] = z4;
  }
  float* myps = ps[wv];

  for (int it = 0; it < 18; ++it){
    int buf = it & 1;
    // stage tile it into LDS (waits vmcnt on gKr/gVr, loaded last iter)
    *(uvec4*)(kw + buf*2048) = gKr;
    *(uvec4*)(vw + buf*2048) = gVr;
    __syncthreads();
    // issue next-tile loads immediately; consumed by next iter's ds_write
    if (it < 17){
      gKr = *(const uvec4*)(kg + (it+1)*2048);
      gVr = *(const uvec4*)(vg + (it+1)*64);
    }
    const unsigned short* kb = Kb[buf];
    const unsigned short* vb = Vb[buf];
    short8 aK[4], aV[2][2];
    #pragma unroll
    for (int g = 0; g < 4; ++g)
      aK[g] = *(const short8*)(kb + (g*16 + lc)*32 + kcol);
    #pragma unroll
    for (int dhg = 0; dhg < 2; ++dhg)
      #pragma unroll
      for (int mh = 0; mh < 2; ++mh)
        aV[dhg][mh] = *(const short8*)(vb + (dhg*16 + lc)*64 + (((mh*4 + lq) ^ (lc&7))*8));
    // S = QK^T (transposed) + bias; exp2; pack; write P scratch
    #pragma unroll
    for (int qf = 0; qf < 2; ++qf){
      #pragma unroll
      for (int g = 0; g < 4; ++g){
        f32x4 S = __builtin_amdgcn_mfma_f32_16x16x32_bf16(aK[g], aQ[qf], c0r[g], 0, 0, 0);
        uvec2 w2;
        w2.x = pack2bf(__builtin_amdgcn_exp2f(S[0]), __builtin_amdgcn_exp2f(S[1]));
        w2.y = pack2bf(__builtin_amdgcn_exp2f(S[2]), __builtin_amdgcn_exp2f(S[3]));
        *(uvec2*)&myps[qf*512 + wbase + ((g*8 + lq*2) ^ sxm)] = w2;
      }
    }
    // prefetch next-tile bias after last S use of c0r
    if (it < 17){
      #pragma unroll
      for (int g = 0; g < 4; ++g)
        c0r[g] = *(const fvec4*)(brow + (it+1)*64 + g*16 + lq*4);
    }
    // PV + row-sum (ones) MFMAs
    __builtin_amdgcn_s_setprio(1);
    #pragma unroll
    for (int qf = 0; qf < 2; ++qf){
      #pragma unroll
      for (int mh = 0; mh < 2; ++mh){
        int d0 = (mh*16 + lq*4) ^ sxm;
        uvec2 lo = *(const uvec2*)&myps[qf*512 + wbase + d0];
        uvec2 hi = *(const uvec2*)&myps[qf*512 + wbase + (d0 ^ 2)];
        uvec4 up; up.x = lo.x; up.y = lo.y; up.z = hi.x; up.w = hi.y;
        short8 bP = __builtin_bit_cast(short8, up);
        Ol[qf] = __builtin_amdgcn_mfma_f32_16x16x32_bf16(aOnes, bP, Ol[qf], 0, 0, 0);
        #pragma unroll
        for (int dhg = 0; dhg < 2; ++dhg)
          O[qf][dhg] = __builtin_amdgcn_mfma_f32_16x16x32_bf16(aV[dhg][mh], bP, O[qf][dhg], 0, 0, 0);
      }
    }
    __builtin_amdgcn_s_setprio(0);
  }
  // store bf16 O partials [b][n][og] (og = h*32 + d), f32 l partials
  #pragma unroll
  for (int qf = 0; qf < 2; ++qf){
    int nidx = nb0 + qf*16 + lc;
    if (lq == 0) lp[b*NSP + nidx] = Ol[qf][0];
    #pragma unroll
    for (int dh = 0; dh < 2; ++dh){
      uvec2 u;
      u.x = pack2bf(O[qf][dh][0], O[qf][dh][1]);
      u.y = pack2bf(O[qf][dh][2], O[qf][dh][3]);
      *(uvec2*)(op + ((size_t)(b*NSP + nidx))*256 + h*32 + dh*16 + lq*4) = u;
    }
  }
}

// ---------------------------------------------------------------------------
// K7: out[c][n] = (sum_o wproj[c][o]*(a0+a1)[o][n]) * rl[n] + bproj[c].
// bf16 MFMA, kc loop register double-buffered; a0/a1 combined through the
// MFMA C chain. grid (72 nt(32 n), 2 ct(128 c), 4 b); wave: 32 c x 32 n.
__global__ __launch_bounds__(256) void k7_proj(const unsigned short* __restrict__ a0,
    const unsigned short* __restrict__ a1, const float* __restrict__ l0p,
    const float* __restrict__ l1p, const unsigned short* __restrict__ wprojb,
    const float* __restrict__ bproj, float* __restrict__ out){
  int nt = blockIdx.x, ct = blockIdx.y, b = blockIdx.z;
  int t = threadIdx.x, wv = t >> 6, lane = t & 63;
  int lq = lane >> 4, lc = lane & 15;
  __shared__ float rls[32];
  if (t < 32) rls[t] = 1.0f / (l0p[b*NSP + nt*32 + t] + l1p[b*NSP + nt*32 + t]);
  __syncthreads();
  int cb = ct*128 + wv*32;
  const f32x4 z4 = {0.f, 0.f, 0.f, 0.f};
  f32x4 acc[2][2];
  #pragma unroll
  for (int ch = 0; ch < 2; ++ch)
    #pragma unroll
    for (int nq = 0; nq < 2; ++nq) acc[ch][nq] = z4;

  const unsigned short* wpp = wprojb + (cb + lc)*256 + lq*8;
  const unsigned short* a0p = a0 + ((size_t)(b*NSP + nt*32 + lc))*256 + lq*8;
  const unsigned short* a1p = a1 + ((size_t)(b*NSP + nt*32 + lc))*256 + lq*8;

  short8 W0[2], W1[2], p00[2], p01[2], p10[2], p11[2];
  auto loadS = [&](short8 (&W)[2], short8 (&B0)[2], short8 (&B1)[2], int kc){
    #pragma unroll
    for (int ch = 0; ch < 2; ++ch) W[ch] = *(const short8*)(wpp + ch*16*256 + kc*32);
    #pragma unroll
    for (int nq = 0; nq < 2; ++nq){
      B0[nq] = *(const short8*)(a0p + (size_t)nq*16*256 + kc*32);
      B1[nq] = *(const short8*)(a1p + (size_t)nq*16*256 + kc*32);
    }
  };
  auto mmS = [&](short8 (&W)[2], short8 (&B0)[2], short8 (&B1)[2]){
    #pragma unroll
    for (int ch = 0; ch < 2; ++ch)
      #pragma unroll
      for (int nq = 0; nq < 2; ++nq){
        acc[ch][nq] = __builtin_amdgcn_mfma_f32_16x16x32_bf16(W[ch], B0[nq], acc[ch][nq], 0, 0, 0);
        acc[ch][nq] = __builtin_amdgcn_mfma_f32_16x16x32_bf16(W[ch], B1[nq], acc[ch][nq], 0, 0, 0);
      }
  };
  loadS(W0, p00, p10, 0);
  for (int kc2 = 0; kc2 < 4; ++kc2){
    loadS(W1, p01, p11, kc2*2+1);
    mmS(W0, p00, p10);
    int kn = (kc2*2+2) & 7;          // 8 wraps to 0: harmless warm reload
    loadS(W0, p00, p10, kn);
    mmS(W1, p01, p11);
  }

  #pragma unroll
  for (int ch = 0; ch < 2; ++ch){
    #pragma unroll
    for (int nq = 0; nq < 2; ++nq){
      int n = nt*32 + nq*16 + lc;
      float rl = rls[nq*16 + lc];
      #pragma unroll
      for (int r = 0; r < 4; ++r){
        int c = cb + ch*16 + lq*4 + r;
        out[((size_t)(b*256 + c))*NSP + n] = acc[ch][nq][r]*rl + bproj[c];
      }
    }
  }
}

// ---------------------------------------------------------------------------
extern "C" void kernel_launch(void* const* d_in, const int* in_sizes, int n_in,
                              void* d_out, int out_size, void* d_ws, size_t ws_size,
                              hipStream_t stream) {
  const float* x     = (const float*)d_in[0];
  const float* rgb   = (const float*)d_in[1];
  const float* wq    = (const float*)d_in[2];
  const float* bq    = (const float*)d_in[3];
  const float* wk    = (const float*)d_in[4];
  const float* bk    = (const float*)d_in[5];
  const float* wv    = (const float*)d_in[6];
  const float* bv    = (const float*)d_in[7];
  const float* wproj = (const float*)d_in[8];
  const float* bproj = (const float*)d_in[9];
  const float* c1w   = (const float*)d_in[10];
  const float* c1b   = (const float*)d_in[11];
  const float* c2w   = (const float*)d_in[12];
  const float* c2b   = (const float*)d_in[13];
  const float* gq_w  = (const float*)d_in[14];
  const float* gq_b  = (const float*)d_in[15];
  const float* bqf_w = (const float*)d_in[16];
  const float* bqf_b = (const float*)d_in[17];
  const float* gk_w  = (const float*)d_in[18];
  const float* gk_b  = (const float*)d_in[19];
  const float* bkf_w = (const float*)d_in[20];
  const float* bkf_b = (const float*)d_in[21];
  const float* gv_w  = (const float*)d_in[22];
  const float* gv_b  = (const float*)d_in[23];
  const float* bvf_w = (const float*)d_in[24];
  const float* bvf_b = (const float*)d_in[25];
  const float* alphaP= (const float*)d_in[26];

  char* w = (char*)d_ws;
  float* luma_n = (float*)w;            w += 4*NSP*4;             // 36864
  float* bias_a = (float*)w;            w += 4*NSP*4;             // 36864
  float* hm_sum = (float*)w;            w += 512*4;               // 2048
  float* film   = (float*)w;            w += 6*4*256*4;           // 24576
  unsigned short* h1p = (unsigned short*)w; w += 4*2500*128*2;    // 2,560,000 (padded bf16)
  unsigned short* wtb = (unsigned short*)w; w += 9*128*128*2;     // 294,912
  unsigned short* wqkvb = (unsigned short*)w; w += 3*256*256*2;   // 393,216
  unsigned short* wprojb = (unsigned short*)w; w += 256*256*2;    // 131,072
  unsigned short* xt  = (unsigned short*)w; w += (size_t)4*NSP*256*2; // 4,718,592
  unsigned short* q_t = (unsigned short*)w; w += (size_t)4*8*NSP*32*2; // 4,718,592
  unsigned short* k_t = (unsigned short*)w; w += (size_t)4*8*NSP*32*2; // 4,718,592
  unsigned short* v_b = (unsigned short*)w; w += (size_t)4*256*NSP*2;  // 4,718,592
  unsigned short* o_part0 = (unsigned short*)w; w += (size_t)4*NSP*256*2; // 4,718,592
  unsigned short* o_part1 = (unsigned short*)w; w += (size_t)4*NSP*256*2; // 4,718,592
  float* l_part0 = (float*)w;           w += 4*NSP*4;             // 36864
  float* l_part1 = (float*)w;           w += 4*NSP*4;             // 36864
  // total ~31.9 MB

  k_prep  <<<2180, 256, 0, stream>>>(c2w, wq, wk, wv, wproj, x, rgb, alphaP,
                                     wtb, wqkvb, wprojb, xt,
                                     luma_n, bias_a, hm_sum, h1p);
  k2_conv1<<<dim3(9,4,4), 256, 0, stream>>>(luma_n, c1w, c1b, h1p);
  k3_conv2<<<dim3(48,2,4), 256, 0, stream>>>(h1p, wtb, c2b, hm_sum);
  k4_film <<<24, 256, 0, stream>>>(hm_sum, gq_w, gq_b, bqf_w, bqf_b,
                                   gk_w, gk_b, bkf_w, bkf_b,
                                   gv_w, gv_b, bvf_w, bvf_b, film);
  k5_qkv  <<<dim3(36,6,4), 256, 0, stream>>>(xt, wqkvb, bq, bk, bv, film,
                                             q_t, k_t, v_b);
  k6_attn <<<dim3(36,8,4), 256, 0, stream>>>(q_t, k_t, v_b, bias_a,
                                             o_part0, o_part1, l_part0, l_part1);
  k7_proj <<<dim3(72,2,4), 256, 0, stream>>>(o_part0, o_part1, l_part0, l_part1,
                                             wprojb, bproj, (float*)d_out);
}